// Round 1
// baseline (677.841 us; speedup 1.0000x reference)
//
#include <hip/hip_runtime.h>
#include <hip/hip_bf16.h>
#include <stdint.h>

typedef unsigned short u16;
typedef __bf16 bf16x8 __attribute__((ext_vector_type(8)));
typedef float f32x4 __attribute__((ext_vector_type(4)));

// B=4, L=1024, A=8, D=1024, H=16, DK=64
#define MROWS 32768   // B*L*A
#define NDIM  1024
#define KDIM  1024

__device__ __forceinline__ void gload_lds16(const void* g, void* l) {
  __builtin_amdgcn_global_load_lds(
      (__attribute__((address_space(1))) const void*)g,
      (__attribute__((address_space(3))) void*)l,
      16, 0, 0);
}

__global__ __launch_bounds__(256) void cvt_w_kernel(const float* __restrict__ s,
                                                    u16* __restrict__ d) {
  const int i = (blockIdx.x * 256 + threadIdx.x) * 8;
  const float4 f0 = *(const float4*)(s + i);
  const float4 f1 = *(const float4*)(s + i + 4);
  bf16x8 h;
  h[0] = (__bf16)f0.x; h[1] = (__bf16)f0.y; h[2] = (__bf16)f0.z; h[3] = (__bf16)f0.w;
  h[4] = (__bf16)f1.x; h[5] = (__bf16)f1.y; h[6] = (__bf16)f1.z; h[7] = (__bf16)f1.w;
  *(bf16x8*)((void*)(d + i)) = h;
}

// C[m,n] = sum_k A[m,k] * B[n,k] + bias[n]   (NT GEMM, 128x128 tile, BK=32)
// A_F32: A is fp32 in global, converted to bf16 during reg->LDS staging.
//        else A is bf16 and staged via global_load_lds.
// OUT_F32: C stored fp32, else bf16.
template <bool A_F32, bool OUT_F32>
__global__ __launch_bounds__(256) void gemm_bt(const void* __restrict__ Av,
                                               const u16* __restrict__ Bw,
                                               const float* __restrict__ bias,
                                               void* __restrict__ Cv,
                                               int M, int N, int K) {
  constexpr int BK = 32;
  __shared__ __align__(16) u16 As[128 * BK];
  __shared__ __align__(16) u16 Bs[128 * BK];

  const int nbx = N >> 7;
  const int bx = (int)blockIdx.x % nbx;
  const int by = (int)blockIdx.x / nbx;
  const int t = threadIdx.x;
  const int lane = t & 63;
  const int wid = t >> 6;
  const int wm = wid >> 1;   // 2x2 waves -> 64x64 each
  const int wn = wid & 1;

  // async staging mapping: 16B (8 bf16) per thread per issue, 2 issues/tile
  const int r0 = t >> 2;
  const int c0 = (t & 3) * 8;
  const int r1 = (t + 256) >> 2;   // = r0 + 64
  const u16* gB0 = Bw + (size_t)(bx * 128 + r0) * K + c0;
  const u16* gB1 = Bw + (size_t)(bx * 128 + r1) * K + c0;
  u16* lB0 = &Bs[(wid * 64) * 8];
  u16* lB1 = &Bs[(256 + wid * 64) * 8];

  // A fp32 reg-staging mapping: 16 floats per thread (one half-row of the tile)
  const int rowa = t >> 1;
  const int ca = (t & 1) * 16;
  const float* gAf = (const float*)Av + (size_t)(by * 128 + rowa) * K + ca;
  // A bf16 async mapping
  const u16* gA0 = (const u16*)Av + (size_t)(by * 128 + r0) * K + c0;
  const u16* gA1 = (const u16*)Av + (size_t)(by * 128 + r1) * K + c0;
  u16* lA0 = &As[(wid * 64) * 8];
  u16* lA1 = &As[(256 + wid * 64) * 8];

  f32x4 acc[4][4] = {};

  const int ar = lane & 15;
  const int kq = (lane >> 4) * 8;

  for (int kt = 0; kt < K; kt += BK) {
    if constexpr (A_F32) {
      const float* ga = gAf + kt;
      const float4 f0 = ((const float4*)ga)[0];
      const float4 f1 = ((const float4*)ga)[1];
      const float4 f2 = ((const float4*)ga)[2];
      const float4 f3 = ((const float4*)ga)[3];
      bf16x8 h0, h1;
      h0[0] = (__bf16)f0.x; h0[1] = (__bf16)f0.y; h0[2] = (__bf16)f0.z; h0[3] = (__bf16)f0.w;
      h0[4] = (__bf16)f1.x; h0[5] = (__bf16)f1.y; h0[6] = (__bf16)f1.z; h0[7] = (__bf16)f1.w;
      h1[0] = (__bf16)f2.x; h1[1] = (__bf16)f2.y; h1[2] = (__bf16)f2.z; h1[3] = (__bf16)f2.w;
      h1[4] = (__bf16)f3.x; h1[5] = (__bf16)f3.y; h1[6] = (__bf16)f3.z; h1[7] = (__bf16)f3.w;
      *(bf16x8*)((void*)&As[rowa * BK + ca]) = h0;
      *(bf16x8*)((void*)&As[rowa * BK + ca + 8]) = h1;
    } else {
      gload_lds16(gA0 + kt, lA0);
      gload_lds16(gA1 + kt, lA1);
    }
    gload_lds16(gB0 + kt, lB0);
    gload_lds16(gB1 + kt, lB1);
    __syncthreads();

    bf16x8 af[4], bfr[4];
#pragma unroll
    for (int m = 0; m < 4; ++m)
      af[m] = *(const bf16x8*)((const void*)&As[(wm * 64 + m * 16 + ar) * BK + kq]);
#pragma unroll
    for (int n = 0; n < 4; ++n)
      bfr[n] = *(const bf16x8*)((const void*)&Bs[(wn * 64 + n * 16 + ar) * BK + kq]);
#pragma unroll
    for (int m = 0; m < 4; ++m)
#pragma unroll
      for (int n = 0; n < 4; ++n)
        acc[m][n] = __builtin_amdgcn_mfma_f32_16x16x32_bf16(af[m], bfr[n], acc[m][n], 0, 0, 0);
    __syncthreads();
  }

  // epilogue: C/D layout col = lane&15, row = (lane>>4)*4 + j
  const int col0 = bx * 128 + wn * 64 + ar;
  const int row0 = by * 128 + wm * 64 + (lane >> 4) * 4;
#pragma unroll
  for (int n = 0; n < 4; ++n) {
    const int gc = col0 + n * 16;
    const float bv = bias[gc];
#pragma unroll
    for (int m = 0; m < 4; ++m) {
#pragma unroll
      for (int j = 0; j < 4; ++j) {
        const size_t idx = (size_t)(row0 + m * 16 + j) * (size_t)N + (size_t)gc;
        const float val = acc[m][n][j] + bv;
        if constexpr (OUT_F32)
          ((float*)Cv)[idx] = val;
        else
          ((u16*)Cv)[idx] = __builtin_bit_cast(u16, (__bf16)val);
      }
    }
  }
}

// One wave per (b,l,h) attention unit: 8x8 scores over DK=64, softmax over e,
// PV, write x in-place over q (disjoint columns per head -> race-free).
__global__ __launch_bounds__(256) void attn_kernel(u16* __restrict__ qx,
                                                   const u16* __restrict__ kb,
                                                   const u16* __restrict__ vb) {
  __shared__ __align__(16) u16 qs[4][8][64];
  __shared__ __align__(16) u16 ks[4][8][64];
  __shared__ __align__(16) u16 vs[4][8][64];
  const int t = threadIdx.x;
  const int lane = t & 63;
  const int w = t >> 6;
  const int unit = blockIdx.x * 4 + w;   // (b*L + l)*16 + h
  const int bl = unit >> 4;
  const int h = unit & 15;
  const int row = lane >> 3;             // attribute index a (load + output row)
  const int c8 = (lane & 7) * 8;         // dk sub-block
  const size_t goff = (size_t)bl * 8 * 1024 + (size_t)h * 64 + (size_t)row * 1024 + c8;

  *(int4*)((void*)&qs[w][row][c8]) = *(const int4*)((const void*)&qx[goff]);
  *(int4*)((void*)&ks[w][row][c8]) = *(const int4*)((const void*)&kb[goff]);
  *(int4*)((void*)&vs[w][row][c8]) = *(const int4*)((const void*)&vb[goff]);
  __syncthreads();

  // lane -> (a = lane>>3, e = lane&7): one score each
  const int a = row;
  const int e = lane & 7;
  float s = 0.f;
#pragma unroll
  for (int d8 = 0; d8 < 64; d8 += 8) {
    const bf16x8 qv = *(const bf16x8*)((const void*)&qs[w][a][d8]);
    const bf16x8 kv = *(const bf16x8*)((const void*)&ks[w][e][d8]);
#pragma unroll
    for (int j = 0; j < 8; ++j) s += (float)qv[j] * (float)kv[j];
  }
  s *= 0.125f;  // 1/sqrt(DK)

  float mx = s;
#pragma unroll
  for (int o = 1; o < 8; o <<= 1) mx = fmaxf(mx, __shfl_xor(mx, o));
  float p = __expf(s - mx);
  float sum = p;
#pragma unroll
  for (int o = 1; o < 8; o <<= 1) sum += __shfl_xor(sum, o);
  p /= sum;

  // x[a, c8..c8+7] = sum_e p[a][e] * v[e][c8..c8+7]
  float xo[8] = {};
#pragma unroll
  for (int e2 = 0; e2 < 8; ++e2) {
    const float pe = __shfl(p, (lane & 56) + e2);
    const bf16x8 vv = *(const bf16x8*)((const void*)&vs[w][e2][c8]);
#pragma unroll
    for (int j = 0; j < 8; ++j) xo[j] += pe * (float)vv[j];
  }
  bf16x8 hx;
#pragma unroll
  for (int j = 0; j < 8; ++j) hx[j] = (__bf16)xo[j];
  *(int4*)((void*)&qx[goff]) = __builtin_bit_cast(int4, hx);
}

extern "C" void kernel_launch(void* const* d_in, const int* in_sizes, int n_in,
                              void* d_out, int out_size, void* d_ws, size_t ws_size,
                              hipStream_t stream) {
  const float* query = (const float*)d_in[0];
  const float* key   = (const float*)d_in[1];
  const float* value = (const float*)d_in[2];
  const float* Wq = (const float*)d_in[3];
  const float* bq = (const float*)d_in[4];
  const float* Wk = (const float*)d_in[5];
  const float* bk = (const float*)d_in[6];
  const float* Wv = (const float*)d_in[7];
  const float* bv = (const float*)d_in[8];
  const float* Wo = (const float*)d_in[9];
  const float* bo = (const float*)d_in[10];
  (void)in_sizes; (void)n_in; (void)out_size; (void)ws_size;

  const int M = MROWS, N = NDIM, K = KDIM;
  const size_t mn = (size_t)M * (size_t)N;   // 33554432 elements

  // Scratch layout:
  //   d_out (134MB fp32 capacity) temporarily holds kb+vb (2x 67MB bf16),
  //   both dead before the final GEMM overwrites d_out with fp32 results.
  //   ws holds qb (67MB bf16, overwritten in-place by attention x) + bf16 weights (8MB).
  u16* kb = (u16*)d_out;
  u16* vb = kb + mn;
  u16* qb = (u16*)d_ws;
  u16* Wqb = qb + mn;
  u16* Wkb = Wqb + 1048576;
  u16* Wvb = Wkb + 1048576;
  u16* Wob = Wvb + 1048576;

  // 1) weights fp32 -> bf16
  cvt_w_kernel<<<512, 256, 0, stream>>>(Wq, Wqb);
  cvt_w_kernel<<<512, 256, 0, stream>>>(Wk, Wkb);
  cvt_w_kernel<<<512, 256, 0, stream>>>(Wv, Wvb);
  cvt_w_kernel<<<512, 256, 0, stream>>>(Wo, Wob);

  // 2) projections (A fp32 -> bf16 staged; out bf16 + bias)
  const int gemm_grid = (M / 128) * (N / 128);  // 2048
  gemm_bt<true, false><<<gemm_grid, 256, 0, stream>>>((const void*)key,   Wkb, bk, (void*)kb, M, N, K);
  gemm_bt<true, false><<<gemm_grid, 256, 0, stream>>>((const void*)value, Wvb, bv, (void*)vb, M, N, K);
  gemm_bt<true, false><<<gemm_grid, 256, 0, stream>>>((const void*)query, Wqb, bq, (void*)qb, M, N, K);

  // 3) attention over attribute axis, in-place x -> qb
  attn_kernel<<<16384, 256, 0, stream>>>(qb, kb, vb);

  // 4) output projection (A bf16 async; out fp32 + bias) -> d_out
  gemm_bt<false, true><<<gemm_grid, 256, 0, stream>>>((const void*)qb, Wob, bo, d_out, M, N, K);
}

// Round 2
// 659.093 us; speedup vs baseline: 1.0284x; 1.0284x over previous
//
#include <hip/hip_runtime.h>
#include <hip/hip_bf16.h>
#include <stdint.h>

typedef unsigned short u16;
typedef __bf16 bf16x8 __attribute__((ext_vector_type(8)));
typedef float f32x4 __attribute__((ext_vector_type(4)));

// B=4, L=1024, A=8, D=1024, H=16, DK=64
#define MROWS 32768   // B*L*A
#define NDIM  1024
#define KDIM  1024

__device__ __forceinline__ void gload_lds16(const void* g, void* l) {
  __builtin_amdgcn_global_load_lds(
      (__attribute__((address_space(1))) const void*)g,
      (__attribute__((address_space(3))) void*)l,
      16, 0, 0);
}

__global__ __launch_bounds__(256) void cvt_w_kernel(const float* __restrict__ s,
                                                    u16* __restrict__ d) {
  const int i = (blockIdx.x * 256 + threadIdx.x) * 8;
  const float4 f0 = *(const float4*)(s + i);
  const float4 f1 = *(const float4*)(s + i + 4);
  bf16x8 h;
  h[0] = (__bf16)f0.x; h[1] = (__bf16)f0.y; h[2] = (__bf16)f0.z; h[3] = (__bf16)f0.w;
  h[4] = (__bf16)f1.x; h[5] = (__bf16)f1.y; h[6] = (__bf16)f1.z; h[7] = (__bf16)f1.w;
  *(bf16x8*)((void*)(d + i)) = h;
}

// C[m,n] = sum_k A[m,k] * B[n,k] + bias[n]   (NT GEMM, 128x128 tile, BK=32)
// A_F32: A fp32 in global, staged to LDS as fp32 via global_load_lds with an
//        XOR chunk swizzle (j_phys = j ^ (r&7)) applied to BOTH the staging
//        source addresses and the fragment-read offsets; cvt to bf16 at
//        fragment read. Else A bf16, linear LDS via global_load_lds.
// OUT_F32: C stored fp32, else bf16.
template <bool A_F32, bool OUT_F32>
__global__ __launch_bounds__(256) void gemm_bt(const void* __restrict__ Av,
                                               const u16* __restrict__ Bw,
                                               const float* __restrict__ bias,
                                               void* __restrict__ Cv,
                                               int M, int N, int K) {
  constexpr int BK = 32;
  constexpr int ABYTES = A_F32 ? 128 * BK * 4 : 128 * BK * 2;
  __shared__ __align__(16) unsigned char As[ABYTES];
  __shared__ __align__(16) u16 Bs[128 * BK];

  const int nbx = N >> 7;                    // 8
  // XCD swizzle: hardware round-robins consecutive blockIdx across the 8 XCDs.
  // Map so all blocks sharing one A-panel (same by) land on the SAME XCD ->
  // the 512KB/256KB panel stays in that XCD's 4MB L2. grid%8==0, per%nbx==0.
  const int bid = (int)blockIdx.x;
  const int per = (int)gridDim.x >> 3;       // blocks per XCD (256)
  const int byper = per / nbx;               // by values per XCD (32)
  const int xcd = bid & 7;
  const int within = bid >> 3;
  const int by = xcd * byper + within / nbx;
  const int bx = within % nbx;

  const int t = threadIdx.x;
  const int lane = t & 63;
  const int wid = t >> 6;
  const int wm = wid >> 1;   // 2x2 waves -> 64x64 each
  const int wn = wid & 1;

  // ---- staging descriptors (16B chunks; LDS dest = wave-uniform base + lane*16) ----
  const u16* gB[2]; u16* lB[2];
#pragma unroll
  for (int i = 0; i < 2; ++i) {
    const int n = i * 256 + t;
    gB[i] = Bw + (size_t)(bx * 128 + (n >> 2)) * K + (n & 3) * 8;
    lB[i] = Bs + (size_t)(i * 256 + (t & ~63)) * 8;
  }

  const float* gAf[4]; const u16* gAb[2]; void* lA[4];
  if constexpr (A_F32) {
    const float* Af = (const float*)Av;
#pragma unroll
    for (int i = 0; i < 4; ++i) {
      const int n = i * 256 + t;
      const int r = n >> 3;
      const int j = (n & 7) ^ (r & 7);       // inverse of read-side swizzle
      gAf[i] = Af + (size_t)(by * 128 + r) * K + j * 4;
      lA[i] = (void*)(As + (size_t)(i * 256 + (t & ~63)) * 16);
    }
  } else {
    const u16* Ab = (const u16*)Av;
#pragma unroll
    for (int i = 0; i < 2; ++i) {
      const int n = i * 256 + t;
      gAb[i] = Ab + (size_t)(by * 128 + (n >> 2)) * K + (n & 3) * 8;
      lA[i] = (void*)(As + (size_t)(i * 256 + (t & ~63)) * 16);
    }
  }

  const int ar = lane & 15;
  const int kq = (lane >> 4) * 8;            // k-element offset within BK

  // fragment LDS byte offsets (constant across K loop)
  int aoffs[4][2];
#pragma unroll
  for (int m = 0; m < 4; ++m) {
    const int r = wm * 64 + m * 16 + ar;
    if constexpr (A_F32) {
      const int jb = kq >> 2;                // fp32 chunk: 0,2,4,6
      aoffs[m][0] = r * 128 + (((jb + 0) ^ (r & 7)) << 4);
      aoffs[m][1] = r * 128 + (((jb + 1) ^ (r & 7)) << 4);
    } else {
      aoffs[m][0] = r * 64 + kq * 2;
      aoffs[m][1] = 0;
    }
  }
  int boffs[4];
#pragma unroll
  for (int n = 0; n < 4; ++n)
    boffs[n] = (wn * 64 + n * 16 + ar) * 64 + kq * 2;

  f32x4 acc[4][4] = {};

  for (int kt = 0; kt < K; kt += BK) {
    if constexpr (A_F32) {
#pragma unroll
      for (int i = 0; i < 4; ++i) gload_lds16(gAf[i] + kt, lA[i]);
    } else {
#pragma unroll
      for (int i = 0; i < 2; ++i) gload_lds16(gAb[i] + kt, lA[i]);
    }
#pragma unroll
    for (int i = 0; i < 2; ++i) gload_lds16(gB[i] + kt, lB[i]);
    __syncthreads();

    bf16x8 af[4], bfr[4];
#pragma unroll
    for (int m = 0; m < 4; ++m) {
      if constexpr (A_F32) {
        const f32x4 x0 = *(const f32x4*)((const void*)(As + aoffs[m][0]));
        const f32x4 x1 = *(const f32x4*)((const void*)(As + aoffs[m][1]));
        bf16x8 h;
        h[0] = (__bf16)x0[0]; h[1] = (__bf16)x0[1]; h[2] = (__bf16)x0[2]; h[3] = (__bf16)x0[3];
        h[4] = (__bf16)x1[0]; h[5] = (__bf16)x1[1]; h[6] = (__bf16)x1[2]; h[7] = (__bf16)x1[3];
        af[m] = h;
      } else {
        af[m] = *(const bf16x8*)((const void*)(As + aoffs[m][0]));
      }
    }
#pragma unroll
    for (int n = 0; n < 4; ++n)
      bfr[n] = *(const bf16x8*)((const void*)((const unsigned char*)Bs + boffs[n]));
#pragma unroll
    for (int m = 0; m < 4; ++m)
#pragma unroll
      for (int n = 0; n < 4; ++n)
        acc[m][n] = __builtin_amdgcn_mfma_f32_16x16x32_bf16(af[m], bfr[n], acc[m][n], 0, 0, 0);
    __syncthreads();
  }

  // epilogue: C/D layout col = lane&15, row = (lane>>4)*4 + j
  const int col0 = bx * 128 + wn * 64 + ar;
  const int row0 = by * 128 + wm * 64 + (lane >> 4) * 4;
#pragma unroll
  for (int n = 0; n < 4; ++n) {
    const int gc = col0 + n * 16;
    const float bv = bias[gc];
#pragma unroll
    for (int m = 0; m < 4; ++m) {
#pragma unroll
      for (int j = 0; j < 4; ++j) {
        const size_t idx = (size_t)(row0 + m * 16 + j) * (size_t)N + (size_t)gc;
        const float val = acc[m][n][j] + bv;
        if constexpr (OUT_F32)
          ((float*)Cv)[idx] = val;
        else
          ((u16*)Cv)[idx] = __builtin_bit_cast(u16, (__bf16)val);
      }
    }
  }
}

// One wave per (b,l,h) attention unit: 8x8 scores over DK=64, softmax over e,
// PV, write x in-place over q (disjoint columns per head -> race-free).
__global__ __launch_bounds__(256) void attn_kernel(u16* __restrict__ qx,
                                                   const u16* __restrict__ kb,
                                                   const u16* __restrict__ vb) {
  __shared__ __align__(16) u16 qs[4][8][64];
  __shared__ __align__(16) u16 ks[4][8][64];
  __shared__ __align__(16) u16 vs[4][8][64];
  const int t = threadIdx.x;
  const int lane = t & 63;
  const int w = t >> 6;
  const int unit = blockIdx.x * 4 + w;   // (b*L + l)*16 + h
  const int bl = unit >> 4;
  const int h = unit & 15;
  const int row = lane >> 3;             // attribute index a
  const int c8 = (lane & 7) * 8;         // dk sub-block
  const size_t goff = (size_t)bl * 8 * 1024 + (size_t)h * 64 + (size_t)row * 1024 + c8;

  *(int4*)((void*)&qs[w][row][c8]) = *(const int4*)((const void*)&qx[goff]);
  *(int4*)((void*)&ks[w][row][c8]) = *(const int4*)((const void*)&kb[goff]);
  *(int4*)((void*)&vs[w][row][c8]) = *(const int4*)((const void*)&vb[goff]);
  __syncthreads();

  const int a = row;
  const int e = lane & 7;
  float s = 0.f;
#pragma unroll
  for (int d8 = 0; d8 < 64; d8 += 8) {
    const bf16x8 qv = *(const bf16x8*)((const void*)&qs[w][a][d8]);
    const bf16x8 kv = *(const bf16x8*)((const void*)&ks[w][e][d8]);
#pragma unroll
    for (int j = 0; j < 8; ++j) s += (float)qv[j] * (float)kv[j];
  }
  s *= 0.125f;  // 1/sqrt(DK)

  float mx = s;
#pragma unroll
  for (int o = 1; o < 8; o <<= 1) mx = fmaxf(mx, __shfl_xor(mx, o));
  float p = __expf(s - mx);
  float sum = p;
#pragma unroll
  for (int o = 1; o < 8; o <<= 1) sum += __shfl_xor(sum, o);
  p /= sum;

  float xo[8] = {};
#pragma unroll
  for (int e2 = 0; e2 < 8; ++e2) {
    const float pe = __shfl(p, (lane & 56) + e2);
    const bf16x8 vv = *(const bf16x8*)((const void*)&vs[w][e2][c8]);
#pragma unroll
    for (int j = 0; j < 8; ++j) xo[j] += pe * (float)vv[j];
  }
  bf16x8 hx;
#pragma unroll
  for (int j = 0; j < 8; ++j) hx[j] = (__bf16)xo[j];
  *(int4*)((void*)&qx[goff]) = __builtin_bit_cast(int4, hx);
}

extern "C" void kernel_launch(void* const* d_in, const int* in_sizes, int n_in,
                              void* d_out, int out_size, void* d_ws, size_t ws_size,
                              hipStream_t stream) {
  const float* query = (const float*)d_in[0];
  const float* key   = (const float*)d_in[1];
  const float* value = (const float*)d_in[2];
  const float* Wq = (const float*)d_in[3];
  const float* bq = (const float*)d_in[4];
  const float* Wk = (const float*)d_in[5];
  const float* bk = (const float*)d_in[6];
  const float* Wv = (const float*)d_in[7];
  const float* bv = (const float*)d_in[8];
  const float* Wo = (const float*)d_in[9];
  const float* bo = (const float*)d_in[10];
  (void)in_sizes; (void)n_in; (void)out_size; (void)ws_size;

  const int M = MROWS, N = NDIM, K = KDIM;
  const size_t mn = (size_t)M * (size_t)N;

  // Scratch: d_out temporarily holds kb+vb (bf16), dead before final GEMM
  // overwrites d_out with fp32. ws holds qb (bf16, overwritten in-place by
  // attention) + bf16 weights.
  u16* kb = (u16*)d_out;
  u16* vb = kb + mn;
  u16* qb = (u16*)d_ws;
  u16* Wqb = qb + mn;
  u16* Wkb = Wqb + 1048576;
  u16* Wvb = Wkb + 1048576;
  u16* Wob = Wvb + 1048576;

  cvt_w_kernel<<<512, 256, 0, stream>>>(Wq, Wqb);
  cvt_w_kernel<<<512, 256, 0, stream>>>(Wk, Wkb);
  cvt_w_kernel<<<512, 256, 0, stream>>>(Wv, Wvb);
  cvt_w_kernel<<<512, 256, 0, stream>>>(Wo, Wob);

  const int gemm_grid = (M / 128) * (N / 128);  // 2048
  gemm_bt<true, false><<<gemm_grid, 256, 0, stream>>>((const void*)key,   Wkb, bk, (void*)kb, M, N, K);
  gemm_bt<true, false><<<gemm_grid, 256, 0, stream>>>((const void*)value, Wvb, bv, (void*)vb, M, N, K);
  gemm_bt<true, false><<<gemm_grid, 256, 0, stream>>>((const void*)query, Wqb, bq, (void*)qb, M, N, K);

  attn_kernel<<<16384, 256, 0, stream>>>(qb, kb, vb);

  gemm_bt<false, true><<<gemm_grid, 256, 0, stream>>>((const void*)qb, Wob, bo, d_out, M, N, K);
}

// Round 3
// 650.556 us; speedup vs baseline: 1.0419x; 1.0131x over previous
//
#include <hip/hip_runtime.h>
#include <hip/hip_bf16.h>
#include <stdint.h>

typedef unsigned short u16;
typedef __bf16 bf16x8 __attribute__((ext_vector_type(8)));
typedef float f32x4 __attribute__((ext_vector_type(4)));

// B=4, L=1024, A=8, D=1024, H=16, DK=64
#define MROWS 32768   // B*L*A
#define NDIM  1024
#define KDIM  1024
#define NTILES (KDIM / 32)   // 32 K-tiles of BK=32

__device__ __forceinline__ void gload_lds16(const void* g, void* l) {
  __builtin_amdgcn_global_load_lds(
      (__attribute__((address_space(1))) const void*)g,
      (__attribute__((address_space(3))) void*)l,
      16, 0, 0);
}

__global__ __launch_bounds__(256) void cvt_w_kernel(const float* __restrict__ s,
                                                    u16* __restrict__ d) {
  const int i = (blockIdx.x * 256 + threadIdx.x) * 8;
  const float4 f0 = *(const float4*)(s + i);
  const float4 f1 = *(const float4*)(s + i + 4);
  bf16x8 h;
  h[0] = (__bf16)f0.x; h[1] = (__bf16)f0.y; h[2] = (__bf16)f0.z; h[3] = (__bf16)f0.w;
  h[4] = (__bf16)f1.x; h[5] = (__bf16)f1.y; h[6] = (__bf16)f1.z; h[7] = (__bf16)f1.w;
  *(bf16x8*)((void*)(d + i)) = h;
}

// C[m,n] = sum_k A[m,k]*B[n,k] + bias[n]  (NT GEMM)
// 256x256 tile, BK=32, 512 threads (8 waves, 2M x 4N), per-wave 128x64 output.
// 3-buffer LDS ring, counted vmcnt (prefetch distance 2 K-tiles, never drain
// to 0 in the main loop), 2 phases/tile with raw s_barrier + setprio around
// the MFMA clusters. LDS XOR-swizzle applied on BOTH stage-source addresses
// and fragment-read offsets (involution).
// A_F32: A fp32 staged as fp32 (cvt to bf16 at frag read); C stored bf16.
// else:  A bf16 staged;                                    C stored fp32.
template <bool A_F32>
__global__ __launch_bounds__(512, 2) void gemm256(const void* __restrict__ Av,
                                                  const u16* __restrict__ Bw,
                                                  const float* __restrict__ bias,
                                                  void* __restrict__ Cv) {
  constexpr int ABUF = A_F32 ? 32768 : 16384;   // bytes per K-tile A buffer
  __shared__ __align__(16) unsigned char As[3 * ABUF];
  __shared__ __align__(16) unsigned char Bs[3 * 16384];

  // XCD grouping: 64 consecutive within-XCD slots -> 16 by-panels x 4 bx.
  const int bid = (int)blockIdx.x;
  const int xcd = bid & 7;
  const int within = bid >> 3;
  const int by = xcd * 16 + (within >> 2);
  const int bx = within & 3;

  const int t = threadIdx.x;
  const int lane = t & 63;
  const int wid = t >> 6;
  const int wm = wid >> 2;       // 0..1
  const int wn = wid & 3;        // 0..3
  const int fr = lane & 15;
  const int hi = lane >> 4;      // 0..3

  // ---- staging descriptors (16B chunks, linear LDS dest, pre-swizzled src) ----
  constexpr int NA = A_F32 ? 4 : 2;
  const float* Af = (const float*)Av;
  const u16* Ab = (const u16*)Av;
  size_t aG[NA]; int aL[NA];
#pragma unroll
  for (int i = 0; i < NA; ++i) {
    const int idx = i * 512 + t;
    if constexpr (A_F32) {
      const int r = idx >> 3, ch = idx & 7;            // 8 chunks per 128B row
      aG[i] = (size_t)(by * 256 + r) * KDIM + (size_t)((ch ^ (r & 7)) << 2);
    } else {
      const int r = idx >> 2, ch = idx & 3;            // 4 chunks per 64B row
      aG[i] = (size_t)(by * 256 + r) * KDIM + (size_t)((ch ^ ((r >> 1) & 3)) << 3);
    }
    aL[i] = (i * 512 + (t & ~63)) * 16;                // wave-uniform base
  }
  size_t bG[2]; int bL[2];
#pragma unroll
  for (int i = 0; i < 2; ++i) {
    const int idx = i * 512 + t;
    const int r = idx >> 2, ch = idx & 3;
    bG[i] = (size_t)(bx * 256 + r) * KDIM + (size_t)((ch ^ ((r >> 1) & 3)) << 3);
    bL[i] = (i * 512 + (t & ~63)) * 16;
  }

  auto stage = [&](int kt, int buf) {
#pragma unroll
    for (int i = 0; i < NA; ++i) {
      if constexpr (A_F32)
        gload_lds16(Af + aG[i] + kt * 32, As + buf * ABUF + aL[i]);
      else
        gload_lds16(Ab + aG[i] + kt * 32, As + buf * ABUF + aL[i]);
    }
#pragma unroll
    for (int i = 0; i < 2; ++i)
      gload_lds16(Bw + bG[i] + kt * 32, Bs + buf * 16384 + bL[i]);
  };

  // ---- fragment read offsets (swizzled; r&7 / (r>>1)&3 reduce to fr-only) ----
  int aBase, acol0, acol1;
  if constexpr (A_F32) {
    aBase = (wm * 128 + fr) * 128;
    acol0 = (((hi * 2 + 0) ^ (fr & 7)) << 4);
    acol1 = (((hi * 2 + 1) ^ (fr & 7)) << 4);
  } else {
    aBase = (wm * 128 + fr) * 64;
    acol0 = ((hi ^ ((fr >> 1) & 3)) << 4);
    acol1 = 0;
  }
  const int bBase = (wn * 64 + fr) * 64;
  const int bcol = ((hi ^ ((fr >> 1) & 3)) << 4);

  f32x4 acc[8][4] = {};

  // prologue: stage tiles 0,1; loop waits keep >=1 tile in flight (counted).
  stage(0, 0);
  stage(1, 1);
  int cur = 0, stg = 2;

  for (int kt = 0; kt < NTILES; ++kt) {
    if (kt < NTILES - 1) {
      if constexpr (A_F32)
        asm volatile("s_waitcnt vmcnt(6)" ::: "memory");
      else
        asm volatile("s_waitcnt vmcnt(4)" ::: "memory");
    } else {
      asm volatile("s_waitcnt vmcnt(0)" ::: "memory");
    }
    asm volatile("s_barrier" ::: "memory");
    if (kt + 2 < NTILES) stage(kt + 2, stg);

    const unsigned char* Ac = As + cur * ABUF;
    const unsigned char* Bc = Bs + cur * 16384;

    bf16x8 bfr[4];
#pragma unroll
    for (int n = 0; n < 4; ++n)
      bfr[n] = *(const bf16x8*)(Bc + bBase + n * 1024 + bcol);

#pragma unroll
    for (int mh = 0; mh < 2; ++mh) {
      bf16x8 af[4];
#pragma unroll
      for (int i = 0; i < 4; ++i) {
        const int m = mh * 4 + i;
        if constexpr (A_F32) {
          const f32x4 x0 = *(const f32x4*)(Ac + aBase + m * 2048 + acol0);
          const f32x4 x1 = *(const f32x4*)(Ac + aBase + m * 2048 + acol1);
          bf16x8 h;
          h[0] = (__bf16)x0[0]; h[1] = (__bf16)x0[1]; h[2] = (__bf16)x0[2]; h[3] = (__bf16)x0[3];
          h[4] = (__bf16)x1[0]; h[5] = (__bf16)x1[1]; h[6] = (__bf16)x1[2]; h[7] = (__bf16)x1[3];
          af[i] = h;
        } else {
          af[i] = *(const bf16x8*)(Ac + aBase + m * 1024 + acol0);
        }
      }
      asm volatile("s_barrier" ::: "memory");
      __builtin_amdgcn_sched_barrier(0);
      __builtin_amdgcn_s_setprio(1);
#pragma unroll
      for (int i = 0; i < 4; ++i)
#pragma unroll
        for (int n = 0; n < 4; ++n)
          acc[mh * 4 + i][n] = __builtin_amdgcn_mfma_f32_16x16x32_bf16(
              af[i], bfr[n], acc[mh * 4 + i][n], 0, 0, 0);
      __builtin_amdgcn_s_setprio(0);
      __builtin_amdgcn_sched_barrier(0);
      asm volatile("s_barrier" ::: "memory");
    }
    cur = (cur == 2) ? 0 : cur + 1;
    stg = (stg == 2) ? 0 : stg + 1;
  }

  // epilogue: D col = lane&15 (B/N side), row = hi*4+j (A/M side)
  const int row0 = by * 256 + wm * 128 + hi * 4;
  const int col0 = bx * 256 + wn * 64 + fr;
#pragma unroll
  for (int n = 0; n < 4; ++n) {
    const int gc = col0 + n * 16;
    const float bv = bias[gc];
#pragma unroll
    for (int m = 0; m < 8; ++m) {
#pragma unroll
      for (int j = 0; j < 4; ++j) {
        const size_t idx = (size_t)(row0 + m * 16 + j) * NDIM + (size_t)gc;
        const float val = acc[m][n][j] + bv;
        if constexpr (A_F32)
          ((u16*)Cv)[idx] = __builtin_bit_cast(u16, (__bf16)val);
        else
          ((float*)Cv)[idx] = val;
      }
    }
  }
}

// One wave per (b,l,h) attention unit: 8x8 scores over DK=64, softmax over e,
// PV, write x in-place over q (disjoint columns per head -> race-free).
__global__ __launch_bounds__(256) void attn_kernel(u16* __restrict__ qx,
                                                   const u16* __restrict__ kb,
                                                   const u16* __restrict__ vb) {
  __shared__ __align__(16) u16 qs[4][8][64];
  __shared__ __align__(16) u16 ks[4][8][64];
  __shared__ __align__(16) u16 vs[4][8][64];
  const int t = threadIdx.x;
  const int lane = t & 63;
  const int w = t >> 6;
  const int unit = blockIdx.x * 4 + w;   // (b*L + l)*16 + h
  const int bl = unit >> 4;
  const int h = unit & 15;
  const int row = lane >> 3;
  const int c8 = (lane & 7) * 8;
  const size_t goff = (size_t)bl * 8 * 1024 + (size_t)h * 64 + (size_t)row * 1024 + c8;

  *(int4*)((void*)&qs[w][row][c8]) = *(const int4*)((const void*)&qx[goff]);
  *(int4*)((void*)&ks[w][row][c8]) = *(const int4*)((const void*)&kb[goff]);
  *(int4*)((void*)&vs[w][row][c8]) = *(const int4*)((const void*)&vb[goff]);
  __syncthreads();

  const int a = row;
  const int e = lane & 7;
  float s = 0.f;
#pragma unroll
  for (int d8 = 0; d8 < 64; d8 += 8) {
    const bf16x8 qv = *(const bf16x8*)((const void*)&qs[w][a][d8]);
    const bf16x8 kv = *(const bf16x8*)((const void*)&ks[w][e][d8]);
#pragma unroll
    for (int j = 0; j < 8; ++j) s += (float)qv[j] * (float)kv[j];
  }
  s *= 0.125f;

  float mx = s;
#pragma unroll
  for (int o = 1; o < 8; o <<= 1) mx = fmaxf(mx, __shfl_xor(mx, o));
  float p = __expf(s - mx);
  float sum = p;
#pragma unroll
  for (int o = 1; o < 8; o <<= 1) sum += __shfl_xor(sum, o);
  p /= sum;

  float xo[8] = {};
#pragma unroll
  for (int e2 = 0; e2 < 8; ++e2) {
    const float pe = __shfl(p, (lane & 56) + e2);
    const bf16x8 vv = *(const bf16x8*)((const void*)&vs[w][e2][c8]);
#pragma unroll
    for (int j = 0; j < 8; ++j) xo[j] += pe * (float)vv[j];
  }
  bf16x8 hx;
#pragma unroll
  for (int j = 0; j < 8; ++j) hx[j] = (__bf16)xo[j];
  *(int4*)((void*)&qx[goff]) = __builtin_bit_cast(int4, hx);
}

extern "C" void kernel_launch(void* const* d_in, const int* in_sizes, int n_in,
                              void* d_out, int out_size, void* d_ws, size_t ws_size,
                              hipStream_t stream) {
  const float* query = (const float*)d_in[0];
  const float* key   = (const float*)d_in[1];
  const float* value = (const float*)d_in[2];
  const float* Wq = (const float*)d_in[3];
  const float* bq = (const float*)d_in[4];
  const float* Wk = (const float*)d_in[5];
  const float* bk = (const float*)d_in[6];
  const float* Wv = (const float*)d_in[7];
  const float* bv = (const float*)d_in[8];
  const float* Wo = (const float*)d_in[9];
  const float* bo = (const float*)d_in[10];
  (void)in_sizes; (void)n_in; (void)out_size; (void)ws_size;

  const size_t mn = (size_t)MROWS * (size_t)NDIM;

  // d_out temporarily holds kb+vb (bf16), dead before final GEMM overwrites
  // d_out with fp32. ws holds qb (bf16, overwritten in-place by attention)
  // + bf16 weights (proven 75MB footprint).
  u16* kb = (u16*)d_out;
  u16* vb = kb + mn;
  u16* qb = (u16*)d_ws;
  u16* Wqb = qb + mn;
  u16* Wkb = Wqb + 1048576;
  u16* Wvb = Wkb + 1048576;
  u16* Wob = Wvb + 1048576;

  cvt_w_kernel<<<512, 256, 0, stream>>>(Wq, Wqb);
  cvt_w_kernel<<<512, 256, 0, stream>>>(Wk, Wkb);
  cvt_w_kernel<<<512, 256, 0, stream>>>(Wv, Wvb);
  cvt_w_kernel<<<512, 256, 0, stream>>>(Wo, Wob);

  const int grid = (MROWS / 256) * (NDIM / 256);  // 512 blocks
  gemm256<true><<<grid, 512, 0, stream>>>((const void*)key,   Wkb, bk, (void*)kb);
  gemm256<true><<<grid, 512, 0, stream>>>((const void*)value, Wvb, bv, (void*)vb);
  gemm256<true><<<grid, 512, 0, stream>>>((const void*)query, Wqb, bq, (void*)qb);

  attn_kernel<<<16384, 256, 0, stream>>>(qb, kb, vb);

  gemm256<false><<<grid, 512, 0, stream>>>((const void*)qb, Wob, bo, d_out);
}

// Round 4
// 582.003 us; speedup vs baseline: 1.1647x; 1.1178x over previous
//
#include <hip/hip_runtime.h>
#include <hip/hip_bf16.h>
#include <stdint.h>

typedef unsigned short u16;
typedef __bf16 bf16x8 __attribute__((ext_vector_type(8)));
typedef float f32x4 __attribute__((ext_vector_type(4)));

// B=4, L=1024, A=8, D=1024, H=16, DK=64
#define MROWS 32768   // B*L*A
#define NDIM  1024
#define KDIM  1024
#define NT    (KDIM / 32)   // 32 K-tiles of BK=32

__device__ __forceinline__ void gload_lds16(const void* g, void* l) {
  __builtin_amdgcn_global_load_lds(
      (__attribute__((address_space(1))) const void*)g,
      (__attribute__((address_space(3))) void*)l,
      16, 0, 0);
}

__global__ __launch_bounds__(256) void cvt_w_kernel(const float* __restrict__ s,
                                                    u16* __restrict__ d) {
  const int i = (blockIdx.x * 256 + threadIdx.x) * 8;
  const float4 f0 = *(const float4*)(s + i);
  const float4 f1 = *(const float4*)(s + i + 4);
  bf16x8 h;
  h[0] = (__bf16)f0.x; h[1] = (__bf16)f0.y; h[2] = (__bf16)f0.z; h[3] = (__bf16)f0.w;
  h[4] = (__bf16)f1.x; h[5] = (__bf16)f1.y; h[6] = (__bf16)f1.z; h[7] = (__bf16)f1.w;
  *(bf16x8*)((void*)(d + i)) = h;
}

// C[m,n] = sum_k A[m,k]*B[n,k] + bias[n]  (NT GEMM, 128x128 tile, BK=32,
// 256 threads = 4 waves 2x2, 64x64 per wave).
// Double-buffered LDS, ONE __syncthreads per K-tile; next tile's loads are
// issued during the MFMA phase so the barrier's vmcnt(0) drain overlaps a
// full compute phase. All LDS tiles are [128 rows][32 k] bf16 (64B rows, 4
// chunks of 16B) with XOR chunk swizzle: logical chunk j of row r sits at
// physical chunk j ^ ((r>>1)&3). gload_lds paths pre-swizzle the SOURCE
// address (linear dest); the A_F32 reg-staged path swizzles the ds_write
// address; all frag reads use chunk hi ^ ((fr>>1)&3)  -> 2-way max.
// A_F32: A fp32, reg-prefetch + cvt + ds_write; C stored bf16.
// else:  A bf16 via gload_lds;                  C stored fp32.
template <bool A_F32>
__global__ __launch_bounds__(256, A_F32 ? 3 : 4)
void gemm_db(const void* __restrict__ Av, const u16* __restrict__ Bw,
             const float* __restrict__ bias, void* __restrict__ Cv) {
  __shared__ __align__(16) unsigned char As[2][8192];
  __shared__ __align__(16) unsigned char Bs[2][8192];

  // XCD grouping: 256 consecutive within-XCD slots = 32 A-panels x 8 bx.
  const int bid = (int)blockIdx.x;
  const int xcd = bid & 7;
  const int within = bid >> 3;
  const int by = xcd * 32 + (within >> 3);
  const int bx = within & 7;

  const int t = threadIdx.x;
  const int lane = t & 63;
  const int wid = t >> 6;
  const int wm = wid >> 1;       // 0..1
  const int wn = wid & 1;        // 0..1
  const int fr = lane & 15;
  const int hi = lane >> 4;      // 0..3

  // ---- B staging: gload_lds, pre-swizzled source, linear dest ----
  size_t bG[2]; int bL[2];
#pragma unroll
  for (int i = 0; i < 2; ++i) {
    const int n = i * 256 + t;
    const int r = n >> 2, ch = n & 3;
    bG[i] = (size_t)(bx * 128 + r) * KDIM + (size_t)((ch ^ ((r >> 1) & 3)) << 3);
    bL[i] = (i * 256 + (t & ~63)) * 16;
  }

  // ---- A staging ----
  // A_F32: thread t owns row ra = t>>1, fp32 cols (t&1)*16 .. +15  (2 chunks)
  const int ra = t >> 1;
  const float* gAf = (const float*)Av + (size_t)(by * 128 + ra) * KDIM + (t & 1) * 16;
  const int j0 = (t & 1) * 2;
  const int fA = (ra >> 1) & 3;
  const int wA0 = ra * 64 + (((j0 + 0) ^ fA) << 4);
  const int wA1 = ra * 64 + (((j0 + 1) ^ fA) << 4);
  // bf16: gload_lds like B
  size_t aG[2]; int aL[2];
#pragma unroll
  for (int i = 0; i < 2; ++i) {
    const int n = i * 256 + t;
    const int r = n >> 2, ch = n & 3;
    aG[i] = (size_t)(by * 128 + r) * KDIM + (size_t)((ch ^ ((r >> 1) & 3)) << 3);
    aL[i] = (i * 256 + (t & ~63)) * 16;
  }

  // ---- frag read offsets (swizzled chunk; (r>>1)&3 reduces to (fr>>1)&3) ----
  const int colx = (hi ^ ((fr >> 1) & 3)) << 4;
  int aoff[4], boff[4];
#pragma unroll
  for (int m = 0; m < 4; ++m) aoff[m] = (wm * 64 + m * 16 + fr) * 64 + colx;
#pragma unroll
  for (int n = 0; n < 4; ++n) boff[n] = (wn * 64 + n * 16 + fr) * 64 + colx;

  f32x4 acc[4][4] = {};
  float4 pf0, pf1, pf2, pf3;

  // prologue: tile 0 staging in flight
  if constexpr (A_F32) {
    pf0 = ((const float4*)gAf)[0];
    pf1 = ((const float4*)gAf)[1];
    pf2 = ((const float4*)gAf)[2];
    pf3 = ((const float4*)gAf)[3];
  } else {
#pragma unroll
    for (int i = 0; i < 2; ++i)
      gload_lds16((const u16*)Av + aG[i], &As[0][aL[i]]);
  }
#pragma unroll
  for (int i = 0; i < 2; ++i)
    gload_lds16(Bw + bG[i], &Bs[0][bL[i]]);

  for (int kt = 0; kt < NT; ++kt) {
    const int cur = kt & 1;
    const int nxt = cur ^ 1;

    if constexpr (A_F32) {
      bf16x8 h0, h1;
      h0[0] = (__bf16)pf0.x; h0[1] = (__bf16)pf0.y; h0[2] = (__bf16)pf0.z; h0[3] = (__bf16)pf0.w;
      h0[4] = (__bf16)pf1.x; h0[5] = (__bf16)pf1.y; h0[6] = (__bf16)pf1.z; h0[7] = (__bf16)pf1.w;
      h1[0] = (__bf16)pf2.x; h1[1] = (__bf16)pf2.y; h1[2] = (__bf16)pf2.z; h1[3] = (__bf16)pf2.w;
      h1[4] = (__bf16)pf3.x; h1[5] = (__bf16)pf3.y; h1[6] = (__bf16)pf3.z; h1[7] = (__bf16)pf3.w;
      *(bf16x8*)((void*)&As[cur][wA0]) = h0;
      *(bf16x8*)((void*)&As[cur][wA1]) = h1;
    }

    __syncthreads();   // staged tile kt visible (vmcnt+lgkm drain + barrier)

    bf16x8 af[4], bfr[4];
#pragma unroll
    for (int m = 0; m < 4; ++m)
      af[m] = *(const bf16x8*)((const void*)&As[cur][aoff[m]]);
#pragma unroll
    for (int n = 0; n < 4; ++n)
      bfr[n] = *(const bf16x8*)((const void*)&Bs[cur][boff[n]]);

    // prefetch tile kt+1 during the MFMA phase
    if (kt + 1 < NT) {
      const int ko = (kt + 1) * 32;
      if constexpr (A_F32) {
        const float* g = gAf + ko;
        pf0 = ((const float4*)g)[0];
        pf1 = ((const float4*)g)[1];
        pf2 = ((const float4*)g)[2];
        pf3 = ((const float4*)g)[3];
      } else {
#pragma unroll
        for (int i = 0; i < 2; ++i)
          gload_lds16((const u16*)Av + aG[i] + ko, &As[nxt][aL[i]]);
      }
#pragma unroll
      for (int i = 0; i < 2; ++i)
        gload_lds16(Bw + bG[i] + ko, &Bs[nxt][bL[i]]);
    }

#pragma unroll
    for (int m = 0; m < 4; ++m)
#pragma unroll
      for (int n = 0; n < 4; ++n)
        acc[m][n] = __builtin_amdgcn_mfma_f32_16x16x32_bf16(af[m], bfr[n], acc[m][n], 0, 0, 0);
  }

  // epilogue: D col = lane&15, row = hi*4 + j
  const int col0 = bx * 128 + wn * 64 + fr;
  const int row0 = by * 128 + wm * 64 + hi * 4;
#pragma unroll
  for (int n = 0; n < 4; ++n) {
    const int gc = col0 + n * 16;
    const float bv = bias[gc];
#pragma unroll
    for (int m = 0; m < 4; ++m) {
#pragma unroll
      for (int j = 0; j < 4; ++j) {
        const size_t idx = (size_t)(row0 + m * 16 + j) * NDIM + (size_t)gc;
        const float val = acc[m][n][j] + bv;
        if constexpr (A_F32)
          ((u16*)Cv)[idx] = __builtin_bit_cast(u16, (__bf16)val);
        else
          ((float*)Cv)[idx] = val;
      }
    }
  }
}

// One wave per (b,l,h) attention unit: 8x8 scores over DK=64, softmax over e,
// PV, write x in-place over q (disjoint columns per head -> race-free).
__global__ __launch_bounds__(256) void attn_kernel(u16* __restrict__ qx,
                                                   const u16* __restrict__ kb,
                                                   const u16* __restrict__ vb) {
  __shared__ __align__(16) u16 qs[4][8][64];
  __shared__ __align__(16) u16 ks[4][8][64];
  __shared__ __align__(16) u16 vs[4][8][64];
  const int t = threadIdx.x;
  const int lane = t & 63;
  const int w = t >> 6;
  const int unit = blockIdx.x * 4 + w;   // (b*L + l)*16 + h
  const int bl = unit >> 4;
  const int h = unit & 15;
  const int row = lane >> 3;
  const int c8 = (lane & 7) * 8;
  const size_t goff = (size_t)bl * 8 * 1024 + (size_t)h * 64 + (size_t)row * 1024 + c8;

  *(int4*)((void*)&qs[w][row][c8]) = *(const int4*)((const void*)&qx[goff]);
  *(int4*)((void*)&ks[w][row][c8]) = *(const int4*)((const void*)&kb[goff]);
  *(int4*)((void*)&vs[w][row][c8]) = *(const int4*)((const void*)&vb[goff]);
  __syncthreads();

  const int a = row;
  const int e = lane & 7;
  float s = 0.f;
#pragma unroll
  for (int d8 = 0; d8 < 64; d8 += 8) {
    const bf16x8 qv = *(const bf16x8*)((const void*)&qs[w][a][d8]);
    const bf16x8 kv = *(const bf16x8*)((const void*)&ks[w][e][d8]);
#pragma unroll
    for (int j = 0; j < 8; ++j) s += (float)qv[j] * (float)kv[j];
  }
  s *= 0.125f;

  float mx = s;
#pragma unroll
  for (int o = 1; o < 8; o <<= 1) mx = fmaxf(mx, __shfl_xor(mx, o));
  float p = __expf(s - mx);
  float sum = p;
#pragma unroll
  for (int o = 1; o < 8; o <<= 1) sum += __shfl_xor(sum, o);
  p /= sum;

  float xo[8] = {};
#pragma unroll
  for (int e2 = 0; e2 < 8; ++e2) {
    const float pe = __shfl(p, (lane & 56) + e2);
    const bf16x8 vv = *(const bf16x8*)((const void*)&vs[w][e2][c8]);
#pragma unroll
    for (int j = 0; j < 8; ++j) xo[j] += pe * (float)vv[j];
  }
  bf16x8 hx;
#pragma unroll
  for (int j = 0; j < 8; ++j) hx[j] = (__bf16)xo[j];
  *(int4*)((void*)&qx[goff]) = __builtin_bit_cast(int4, hx);
}

extern "C" void kernel_launch(void* const* d_in, const int* in_sizes, int n_in,
                              void* d_out, int out_size, void* d_ws, size_t ws_size,
                              hipStream_t stream) {
  const float* query = (const float*)d_in[0];
  const float* key   = (const float*)d_in[1];
  const float* value = (const float*)d_in[2];
  const float* Wq = (const float*)d_in[3];
  const float* bq = (const float*)d_in[4];
  const float* Wk = (const float*)d_in[5];
  const float* bk = (const float*)d_in[6];
  const float* Wv = (const float*)d_in[7];
  const float* bv = (const float*)d_in[8];
  const float* Wo = (const float*)d_in[9];
  const float* bo = (const float*)d_in[10];
  (void)in_sizes; (void)n_in; (void)out_size; (void)ws_size;

  const size_t mn = (size_t)MROWS * (size_t)NDIM;

  // d_out temporarily holds kb+vb (bf16), dead before final GEMM overwrites
  // d_out with fp32. ws holds qb (bf16, overwritten in-place by attention)
  // + bf16 weights.
  u16* kb = (u16*)d_out;
  u16* vb = kb + mn;
  u16* qb = (u16*)d_ws;
  u16* Wqb = qb + mn;
  u16* Wkb = Wqb + 1048576;
  u16* Wvb = Wkb + 1048576;
  u16* Wob = Wvb + 1048576;

  cvt_w_kernel<<<512, 256, 0, stream>>>(Wq, Wqb);
  cvt_w_kernel<<<512, 256, 0, stream>>>(Wk, Wkb);
  cvt_w_kernel<<<512, 256, 0, stream>>>(Wv, Wvb);
  cvt_w_kernel<<<512, 256, 0, stream>>>(Wo, Wob);

  const int grid = (MROWS / 128) * (NDIM / 128);  // 2048 blocks
  gemm_db<true><<<grid, 256, 0, stream>>>((const void*)key,   Wkb, bk, (void*)kb);
  gemm_db<true><<<grid, 256, 0, stream>>>((const void*)value, Wvb, bv, (void*)vb);
  gemm_db<true><<<grid, 256, 0, stream>>>((const void*)query, Wqb, bq, (void*)qb);

  attn_kernel<<<16384, 256, 0, stream>>>(qb, kb, vb);

  gemm_db<false><<<grid, 256, 0, stream>>>((const void*)qb, Wob, bo, d_out);
}

// Round 6
// 544.102 us; speedup vs baseline: 1.2458x; 1.0697x over previous
//
#include <hip/hip_runtime.h>
#include <hip/hip_bf16.h>
#include <stdint.h>

typedef unsigned short u16;
typedef __bf16 bf16x8 __attribute__((ext_vector_type(8)));
typedef float f32x4 __attribute__((ext_vector_type(4)));

// B=4, L=1024, A=8, D=1024, H=16, DK=64
#define MROWS 32768   // B*L*A
#define NDIM  1024
#define KDIM  1024
#define NKT   16      // K-tiles of BK=64

__device__ __forceinline__ void gload_lds16(const void* g, void* l) {
  __builtin_amdgcn_global_load_lds(
      (__attribute__((address_space(1))) const void*)g,
      (__attribute__((address_space(3))) void*)l,
      16, 0, 0);
}

struct CvtArgs { const float* s[4]; u16* d[4]; };
struct ProjArgs {
  const float* A[3]; const u16* W[3]; const float* bias[3]; u16* C[3];
};

__global__ __launch_bounds__(256) void cvt4_kernel(CvtArgs ca) {
  const int which = blockIdx.x >> 9;            // 512 blocks per matrix
  const float* s = ca.s[which];
  u16* d = ca.d[which];
  const int i = ((((int)blockIdx.x & 511) * 256) + (int)threadIdx.x) * 8;
  const float4 f0 = *(const float4*)(s + i);
  const float4 f1 = *(const float4*)(s + i + 4);
  bf16x8 h;
  h[0] = (__bf16)f0.x; h[1] = (__bf16)f0.y; h[2] = (__bf16)f0.z; h[3] = (__bf16)f0.w;
  h[4] = (__bf16)f1.x; h[5] = (__bf16)f1.y; h[6] = (__bf16)f1.z; h[7] = (__bf16)f1.w;
  *(bf16x8*)((void*)(d + i)) = h;
}

// ---------------------------------------------------------------------------
// 256x256 tile NT GEMM, BK=64, 512 threads (8 waves 2Mx4N, 128x64 per wave).
// Double-buffered LDS (128KB), ONE __syncthreads per K-tile; prefetch for
// tile kt+1 issued right after the first fragment batch of tile kt so the
// barrier's implicit vmcnt(0) drain is covered by ~64 MFMA/wave.
// LDS tiles: [256 rows][64 bf16] = 128B rows = 8 chunks of 16B, XOR swizzle
// chunk_phys = chunk_log ^ (row&7) applied on BOTH sides (involution):
//   - B (and bf16-A) staging: gload_lds with pre-swizzled SOURCE, linear dest
//   - fp32-A staging: reg-load + cvt + swizzled ds_write
//   - all frag reads: chunk_log = kk*4 + hi, phys = chunk_log ^ (fr&7)
// Per-16-lane phase: 8 slots x 2 lanes -> 2-way max (free; r4 measured 0).
// ---------------------------------------------------------------------------

// Fragment/epilogue geometry shared by both GEMM kernels.
#define GEMM_COMMON_IDX()                                                     \
  const int t = (int)threadIdx.x;                                             \
  const int lane = t & 63;                                                    \
  const int wid = t >> 6;                                                     \
  const int wm = wid >> 2;                                                    \
  const int wn = wid & 3;                                                     \
  const int fr = lane & 15;                                                   \
  const int hi = lane >> 4;

__global__ __launch_bounds__(512, 2) void proj3_kernel(ProjArgs pa) {
  __shared__ __align__(16) unsigned char As[2][32768];
  __shared__ __align__(16) unsigned char Bs[2][32768];

  // XCD grouping: bid&7 = XCD; 64 within-XCD slots per gemm = 16 by x 4 bx.
  const int bid = (int)blockIdx.x;
  const int xcd = bid & 7;
  const int within = bid >> 3;        // 0..191
  const int g = within >> 6;          // 0..2 which projection
  const int w2 = within & 63;
  const int by = xcd * 16 + (w2 >> 2);  // 0..127
  const int bx = w2 & 3;              // 0..3

  const float* Af = pa.A[g];
  const u16* Bw = pa.W[g];
  const float* bias = pa.bias[g];
  u16* C = pa.C[g];

  GEMM_COMMON_IDX();

  // B staging: 2048 16B-chunks, 4 per thread.
  size_t bG[4]; int bL[4];
#pragma unroll
  for (int i = 0; i < 4; ++i) {
    const int idx = i * 512 + t;
    const int r = idx >> 3, ch = idx & 7;
    bG[i] = (size_t)(bx * 256 + r) * KDIM + (size_t)((ch ^ (r & 7)) << 3);
    bL[i] = (i * 512 + (t & ~63)) * 16;
  }

  // A fp32 reg prefetch: thread t owns row ra=t>>1, cols (t&1)*32..+31.
  const int ra = t >> 1;
  const float* gA = Af + (size_t)(by * 256 + ra) * KDIM + (t & 1) * 32;
  int wA[4];
#pragma unroll
  for (int c = 0; c < 4; ++c)
    wA[c] = ra * 128 + (((((t & 1) * 4) + c) ^ (ra & 7)) << 4);

  // frag read offsets
  int aRow[8], bRow[4], colx[2];
#pragma unroll
  for (int m = 0; m < 8; ++m) aRow[m] = (wm * 128 + m * 16 + fr) * 128;
#pragma unroll
  for (int n = 0; n < 4; ++n) bRow[n] = (wn * 64 + n * 16 + fr) * 128;
#pragma unroll
  for (int kk = 0; kk < 2; ++kk) colx[kk] = (((kk * 4 + hi) ^ (fr & 7)) << 4);

  f32x4 acc[8][4] = {};
  float4 pf[8];

  // prologue: tile 0 in flight
#pragma unroll
  for (int i = 0; i < 8; ++i) pf[i] = ((const float4*)gA)[i];
#pragma unroll
  for (int i = 0; i < 4; ++i) gload_lds16(Bw + bG[i], &Bs[0][bL[i]]);

  for (int kt = 0; kt < NKT; ++kt) {
    const int cur = kt & 1, nxt = cur ^ 1;

    // cvt prefetched A regs -> LDS (buf cur): last readers of buf cur
    // finished before the previous barrier.
#pragma unroll
    for (int c = 0; c < 4; ++c) {
      bf16x8 h;
      h[0] = (__bf16)pf[2 * c].x; h[1] = (__bf16)pf[2 * c].y;
      h[2] = (__bf16)pf[2 * c].z; h[3] = (__bf16)pf[2 * c].w;
      h[4] = (__bf16)pf[2 * c + 1].x; h[5] = (__bf16)pf[2 * c + 1].y;
      h[6] = (__bf16)pf[2 * c + 1].z; h[7] = (__bf16)pf[2 * c + 1].w;
      *(bf16x8*)((void*)&As[cur][wA[c]]) = h;
    }
    __syncthreads();

    // kk=0 fragments (first batch)
    bf16x8 bf0[4], a0[4];
#pragma unroll
    for (int n = 0; n < 4; ++n)
      bf0[n] = *(const bf16x8*)((const void*)&Bs[cur][bRow[n] + colx[0]]);
#pragma unroll
    for (int m = 0; m < 4; ++m)
      a0[m] = *(const bf16x8*)((const void*)&As[cur][aRow[m] + colx[0]]);

    // prefetch tile kt+1 (covered by this tile's 64 MFMA/wave)
    if (kt + 1 < NKT) {
      const int ko = (kt + 1) * 64;
      const float* g2 = gA + ko;
#pragma unroll
      for (int i = 0; i < 8; ++i) pf[i] = ((const float4*)g2)[i];
#pragma unroll
      for (int i = 0; i < 4; ++i)
        gload_lds16(Bw + bG[i] + ko, &Bs[nxt][bL[i]]);
    }

    __builtin_amdgcn_s_setprio(1);
#pragma unroll
    for (int m = 0; m < 4; ++m)
#pragma unroll
      for (int n = 0; n < 4; ++n)
        acc[m][n] = __builtin_amdgcn_mfma_f32_16x16x32_bf16(a0[m], bf0[n], acc[m][n], 0, 0, 0);
    __builtin_amdgcn_s_setprio(0);

#pragma unroll
    for (int m = 0; m < 4; ++m)
      a0[m] = *(const bf16x8*)((const void*)&As[cur][aRow[4 + m] + colx[0]]);
    __builtin_amdgcn_s_setprio(1);
#pragma unroll
    for (int m = 0; m < 4; ++m)
#pragma unroll
      for (int n = 0; n < 4; ++n)
        acc[4 + m][n] = __builtin_amdgcn_mfma_f32_16x16x32_bf16(a0[m], bf0[n], acc[4 + m][n], 0, 0, 0);
    __builtin_amdgcn_s_setprio(0);

    // kk=1
#pragma unroll
    for (int n = 0; n < 4; ++n)
      bf0[n] = *(const bf16x8*)((const void*)&Bs[cur][bRow[n] + colx[1]]);
#pragma unroll
    for (int m = 0; m < 4; ++m)
      a0[m] = *(const bf16x8*)((const void*)&As[cur][aRow[m] + colx[1]]);
    __builtin_amdgcn_s_setprio(1);
#pragma unroll
    for (int m = 0; m < 4; ++m)
#pragma unroll
      for (int n = 0; n < 4; ++n)
        acc[m][n] = __builtin_amdgcn_mfma_f32_16x16x32_bf16(a0[m], bf0[n], acc[m][n], 0, 0, 0);
    __builtin_amdgcn_s_setprio(0);
#pragma unroll
    for (int m = 0; m < 4; ++m)
      a0[m] = *(const bf16x8*)((const void*)&As[cur][aRow[4 + m] + colx[1]]);
    __builtin_amdgcn_s_setprio(1);
#pragma unroll
    for (int m = 0; m < 4; ++m)
#pragma unroll
      for (int n = 0; n < 4; ++n)
        acc[4 + m][n] = __builtin_amdgcn_mfma_f32_16x16x32_bf16(a0[m], bf0[n], acc[4 + m][n], 0, 0, 0);
    __builtin_amdgcn_s_setprio(0);
  }

  // epilogue: D col = fr, row = hi*4 + j
  const int row0 = by * 256 + wm * 128 + hi * 4;
  const int col0 = bx * 256 + wn * 64 + fr;
#pragma unroll
  for (int n = 0; n < 4; ++n) {
    const int gc = col0 + n * 16;
    const float bv = bias[gc];
#pragma unroll
    for (int m = 0; m < 8; ++m) {
#pragma unroll
      for (int j = 0; j < 4; ++j) {
        const size_t idx = (size_t)(row0 + m * 16 + j) * NDIM + (size_t)gc;
        C[idx] = __builtin_bit_cast(u16, (__bf16)(acc[m][n][j] + bv));
      }
    }
  }
}

// Final GEMM: A bf16 (attention output), C fp32 + bias.
__global__ __launch_bounds__(512, 2) void gemmo_kernel(const u16* __restrict__ Ab,
                                                       const u16* __restrict__ Bw,
                                                       const float* __restrict__ bias,
                                                       float* __restrict__ C) {
  __shared__ __align__(16) unsigned char As[2][32768];
  __shared__ __align__(16) unsigned char Bs[2][32768];

  const int bid = (int)blockIdx.x;
  const int xcd = bid & 7;
  const int within = bid >> 3;        // 0..63
  const int by = xcd * 16 + (within >> 2);
  const int bx = within & 3;

  GEMM_COMMON_IDX();

  size_t aG[4], bG[4]; int aL[4], bL[4];
#pragma unroll
  for (int i = 0; i < 4; ++i) {
    const int idx = i * 512 + t;
    const int r = idx >> 3, ch = idx & 7;
    const size_t cswz = (size_t)((ch ^ (r & 7)) << 3);
    aG[i] = (size_t)(by * 256 + r) * KDIM + cswz;
    bG[i] = (size_t)(bx * 256 + r) * KDIM + cswz;
    aL[i] = bL[i] = (i * 512 + (t & ~63)) * 16;
  }

  int aRow[8], bRow[4], colx[2];
#pragma unroll
  for (int m = 0; m < 8; ++m) aRow[m] = (wm * 128 + m * 16 + fr) * 128;
#pragma unroll
  for (int n = 0; n < 4; ++n) bRow[n] = (wn * 64 + n * 16 + fr) * 128;
#pragma unroll
  for (int kk = 0; kk < 2; ++kk) colx[kk] = (((kk * 4 + hi) ^ (fr & 7)) << 4);

  f32x4 acc[8][4] = {};

#pragma unroll
  for (int i = 0; i < 4; ++i) {
    gload_lds16(Ab + aG[i], &As[0][aL[i]]);
    gload_lds16(Bw + bG[i], &Bs[0][bL[i]]);
  }

  for (int kt = 0; kt < NKT; ++kt) {
    const int cur = kt & 1, nxt = cur ^ 1;
    __syncthreads();

    bf16x8 bf0[4], a0[4];
#pragma unroll
    for (int n = 0; n < 4; ++n)
      bf0[n] = *(const bf16x8*)((const void*)&Bs[cur][bRow[n] + colx[0]]);
#pragma unroll
    for (int m = 0; m < 4; ++m)
      a0[m] = *(const bf16x8*)((const void*)&As[cur][aRow[m] + colx[0]]);

    if (kt + 1 < NKT) {
      const int ko = (kt + 1) * 64;
#pragma unroll
      for (int i = 0; i < 4; ++i) {
        gload_lds16(Ab + aG[i] + ko, &As[nxt][aL[i]]);
        gload_lds16(Bw + bG[i] + ko, &Bs[nxt][bL[i]]);
      }
    }

    __builtin_amdgcn_s_setprio(1);
#pragma unroll
    for (int m = 0; m < 4; ++m)
#pragma unroll
      for (int n = 0; n < 4; ++n)
        acc[m][n] = __builtin_amdgcn_mfma_f32_16x16x32_bf16(a0[m], bf0[n], acc[m][n], 0, 0, 0);
    __builtin_amdgcn_s_setprio(0);
#pragma unroll
    for (int m = 0; m < 4; ++m)
      a0[m] = *(const bf16x8*)((const void*)&As[cur][aRow[4 + m] + colx[0]]);
    __builtin_amdgcn_s_setprio(1);
#pragma unroll
    for (int m = 0; m < 4; ++m)
#pragma unroll
      for (int n = 0; n < 4; ++n)
        acc[4 + m][n] = __builtin_amdgcn_mfma_f32_16x16x32_bf16(a0[m], bf0[n], acc[4 + m][n], 0, 0, 0);
    __builtin_amdgcn_s_setprio(0);

#pragma unroll
    for (int n = 0; n < 4; ++n)
      bf0[n] = *(const bf16x8*)((const void*)&Bs[cur][bRow[n] + colx[1]]);
#pragma unroll
    for (int m = 0; m < 4; ++m)
      a0[m] = *(const bf16x8*)((const void*)&As[cur][aRow[m] + colx[1]]);
    __builtin_amdgcn_s_setprio(1);
#pragma unroll
    for (int m = 0; m < 4; ++m)
#pragma unroll
      for (int n = 0; n < 4; ++n)
        acc[m][n] = __builtin_amdgcn_mfma_f32_16x16x32_bf16(a0[m], bf0[n], acc[m][n], 0, 0, 0);
    __builtin_amdgcn_s_setprio(0);
#pragma unroll
    for (int m = 0; m < 4; ++m)
      a0[m] = *(const bf16x8*)((const void*)&As[cur][aRow[4 + m] + colx[1]]);
    __builtin_amdgcn_s_setprio(1);
#pragma unroll
    for (int m = 0; m < 4; ++m)
#pragma unroll
      for (int n = 0; n < 4; ++n)
        acc[4 + m][n] = __builtin_amdgcn_mfma_f32_16x16x32_bf16(a0[m], bf0[n], acc[4 + m][n], 0, 0, 0);
    __builtin_amdgcn_s_setprio(0);
  }

  const int row0 = by * 256 + wm * 128 + hi * 4;
  const int col0 = bx * 256 + wn * 64 + fr;
#pragma unroll
  for (int n = 0; n < 4; ++n) {
    const int gc = col0 + n * 16;
    const float bv = bias[gc];
#pragma unroll
    for (int m = 0; m < 8; ++m) {
#pragma unroll
      for (int j = 0; j < 4; ++j) {
        const size_t idx = (size_t)(row0 + m * 16 + j) * NDIM + (size_t)gc;
        C[idx] = acc[m][n][j] + bv;
      }
    }
  }
}

// One wave per (b,l,h) attention unit: 8x8 scores over DK=64, softmax over e,
// PV, write x in-place over q (disjoint columns per head -> race-free).
__global__ __launch_bounds__(256) void attn_kernel(u16* __restrict__ qx,
                                                   const u16* __restrict__ kb,
                                                   const u16* __restrict__ vb) {
  __shared__ __align__(16) u16 qs[4][8][64];
  __shared__ __align__(16) u16 ks[4][8][64];
  __shared__ __align__(16) u16 vs[4][8][64];
  const int t = threadIdx.x;
  const int lane = t & 63;
  const int w = t >> 6;
  const int unit = blockIdx.x * 4 + w;   // (b*L + l)*16 + h
  const int bl = unit >> 4;
  const int h = unit & 15;
  const int row = lane >> 3;
  const int c8 = (lane & 7) * 8;
  const size_t goff = (size_t)bl * 8 * 1024 + (size_t)h * 64 + (size_t)row * 1024 + c8;

  *(int4*)((void*)&qs[w][row][c8]) = *(const int4*)((const void*)&qx[goff]);
  *(int4*)((void*)&ks[w][row][c8]) = *(const int4*)((const void*)&kb[goff]);
  *(int4*)((void*)&vs[w][row][c8]) = *(const int4*)((const void*)&vb[goff]);
  __syncthreads();

  const int a = row;
  const int e = lane & 7;
  float s = 0.f;
#pragma unroll
  for (int d8 = 0; d8 < 64; d8 += 8) {
    const bf16x8 qv = *(const bf16x8*)((const void*)&qs[w][a][d8]);
    const bf16x8 kv = *(const bf16x8*)((const void*)&ks[w][e][d8]);
#pragma unroll
    for (int j = 0; j < 8; ++j) s += (float)qv[j] * (float)kv[j];
  }
  s *= 0.125f;

  float mx = s;
#pragma unroll
  for (int o = 1; o < 8; o <<= 1) mx = fmaxf(mx, __shfl_xor(mx, o));
  float p = __expf(s - mx);
  float sum = p;
#pragma unroll
  for (int o = 1; o < 8; o <<= 1) sum += __shfl_xor(sum, o);
  p /= sum;

  float xo[8] = {};
#pragma unroll
  for (int e2 = 0; e2 < 8; ++e2) {
    const float pe = __shfl(p, (lane & 56) + e2);
    const bf16x8 vv = *(const bf16x8*)((const void*)&vs[w][e2][c8]);
#pragma unroll
    for (int j = 0; j < 8; ++j) xo[j] += pe * (float)vv[j];
  }
  bf16x8 hx;
#pragma unroll
  for (int j = 0; j < 8; ++j) hx[j] = (__bf16)xo[j];
  *(int4*)((void*)&qx[goff]) = __builtin_bit_cast(int4, hx);
}

extern "C" void kernel_launch(void* const* d_in, const int* in_sizes, int n_in,
                              void* d_out, int out_size, void* d_ws, size_t ws_size,
                              hipStream_t stream) {
  const float* query = (const float*)d_in[0];
  const float* key   = (const float*)d_in[1];
  const float* value = (const float*)d_in[2];
  const float* Wq = (const float*)d_in[3];
  const float* bq = (const float*)d_in[4];
  const float* Wk = (const float*)d_in[5];
  const float* bk = (const float*)d_in[6];
  const float* Wv = (const float*)d_in[7];
  const float* bv = (const float*)d_in[8];
  const float* Wo = (const float*)d_in[9];
  const float* bo = (const float*)d_in[10];
  (void)in_sizes; (void)n_in; (void)out_size; (void)ws_size;

  const size_t mn = (size_t)MROWS * (size_t)NDIM;

  // d_out temporarily holds kb+vb (bf16), dead before final GEMM overwrites
  // d_out with fp32. ws holds qb (bf16, overwritten in-place by attention)
  // + bf16 weights.
  u16* kb = (u16*)d_out;
  u16* vb = kb + mn;
  u16* qb = (u16*)d_ws;
  u16* Wqb = qb + mn;
  u16* Wkb = Wqb + 1048576;
  u16* Wvb = Wkb + 1048576;
  u16* Wob = Wvb + 1048576;

  CvtArgs ca;
  ca.s[0] = Wq; ca.s[1] = Wk; ca.s[2] = Wv; ca.s[3] = Wo;
  ca.d[0] = Wqb; ca.d[1] = Wkb; ca.d[2] = Wvb; ca.d[3] = Wob;
  cvt4_kernel<<<2048, 256, 0, stream>>>(ca);

  ProjArgs pa;
  pa.A[0] = key;  pa.A[1] = value; pa.A[2] = query;
  pa.W[0] = Wkb;  pa.W[1] = Wvb;   pa.W[2] = Wqb;
  pa.bias[0] = bk; pa.bias[1] = bv; pa.bias[2] = bq;
  pa.C[0] = kb;   pa.C[1] = vb;    pa.C[2] = qb;
  proj3_kernel<<<1536, 512, 0, stream>>>(pa);

  attn_kernel<<<16384, 256, 0, stream>>>(qb, kb, vb);

  gemmo_kernel<<<512, 512, 0, stream>>>(qb, Wob, bo, (float*)d_out);
}

// Round 7
// 494.914 us; speedup vs baseline: 1.3696x; 1.0994x over previous
//
#include <hip/hip_runtime.h>
#include <hip/hip_bf16.h>
#include <stdint.h>

typedef unsigned short u16;
typedef __bf16 bf16x8 __attribute__((ext_vector_type(8)));
typedef float f32x4 __attribute__((ext_vector_type(4)));

// B=4, L=1024, A=8, D=1024, H=16, DK=64
#define MROWS 32768   // B*L*A
#define NDIM  1024
#define KDIM  1024
#define NKT   16      // K-tiles of BK=64
#define MHALF 16777216  // 16384 rows * 1024 cols (elements per half input)

__device__ __forceinline__ void gload_lds16(const void* g, void* l) {
  __builtin_amdgcn_global_load_lds(
      (__attribute__((address_space(1))) const void*)g,
      (__attribute__((address_space(3))) void*)l,
      16, 0, 0);
}

struct CvtArgs { const float* s[4]; u16* d[4]; };

__global__ __launch_bounds__(256) void cvt4_kernel(CvtArgs ca) {
  const int which = blockIdx.x >> 9;            // 512 blocks per matrix
  const float* s = ca.s[which];
  u16* d = ca.d[which];
  const int i = ((((int)blockIdx.x & 511) * 256) + (int)threadIdx.x) * 8;
  const float4 f0 = *(const float4*)(s + i);
  const float4 f1 = *(const float4*)(s + i + 4);
  bf16x8 h;
  h[0] = (__bf16)f0.x; h[1] = (__bf16)f0.y; h[2] = (__bf16)f0.z; h[3] = (__bf16)f0.w;
  h[4] = (__bf16)f1.x; h[5] = (__bf16)f1.y; h[6] = (__bf16)f1.z; h[7] = (__bf16)f1.w;
  *(bf16x8*)((void*)(d + i)) = h;
}

// fp32 -> bf16 copy-convert for one half-input (16.78M elems, 8192 blocks).
__global__ __launch_bounds__(256) void cvt_half_kernel(const float* __restrict__ s,
                                                       u16* __restrict__ d) {
  const int i = ((int)blockIdx.x * 256 + (int)threadIdx.x) * 8;
  const float4 f0 = *(const float4*)(s + i);
  const float4 f1 = *(const float4*)(s + i + 4);
  bf16x8 h;
  h[0] = (__bf16)f0.x; h[1] = (__bf16)f0.y; h[2] = (__bf16)f0.z; h[3] = (__bf16)f0.w;
  h[4] = (__bf16)f1.x; h[5] = (__bf16)f1.y; h[6] = (__bf16)f1.z; h[7] = (__bf16)f1.w;
  *(bf16x8*)((void*)(d + i)) = h;
}

// ---------------------------------------------------------------------------
// Pure-bf16 256x256 NT GEMM (round-6 gemmo structure, validated):
// BK=64, 512 threads (8 waves 2Mx4N, 128x64 per wave), double-buffered LDS
// (128KB), ONE __syncthreads per K-tile, prefetch for tile kt+1 issued right
// after the first fragment batch (gload_lds both operands, pre-swizzled
// source / linear dest), frag reads use chunk hi ^ (fr&7) -> measured 0
// bank conflicts. setprio(1) around MFMA clusters.
// OUT_F32: C fp32 + bias, else C bf16 + bias.
// byPerXcd: by-panels per XCD (8 for 256-block half-proj, 16 for 512-block).
// ---------------------------------------------------------------------------
template <bool OUT_F32>
__global__ __launch_bounds__(512, 2) void gemm_bt256(const u16* __restrict__ Ab,
                                                     const u16* __restrict__ Bw,
                                                     const float* __restrict__ bias,
                                                     void* __restrict__ Cv,
                                                     int byPerXcd) {
  __shared__ __align__(16) unsigned char As[2][32768];
  __shared__ __align__(16) unsigned char Bs[2][32768];

  const int bid = (int)blockIdx.x;
  const int xcd = bid & 7;
  const int within = bid >> 3;
  const int by = xcd * byPerXcd + (within >> 2);
  const int bx = within & 3;

  const int t = (int)threadIdx.x;
  const int lane = t & 63;
  const int wid = t >> 6;
  const int wm = wid >> 2;
  const int wn = wid & 3;
  const int fr = lane & 15;
  const int hi = lane >> 4;

  size_t aG[4], bG[4]; int aL[4], bL[4];
#pragma unroll
  for (int i = 0; i < 4; ++i) {
    const int idx = i * 512 + t;
    const int r = idx >> 3, ch = idx & 7;
    const size_t cswz = (size_t)((ch ^ (r & 7)) << 3);
    aG[i] = (size_t)(by * 256 + r) * KDIM + cswz;
    bG[i] = (size_t)(bx * 256 + r) * KDIM + cswz;
    aL[i] = bL[i] = (i * 512 + (t & ~63)) * 16;
  }

  int aRow[8], bRow[4], colx[2];
#pragma unroll
  for (int m = 0; m < 8; ++m) aRow[m] = (wm * 128 + m * 16 + fr) * 128;
#pragma unroll
  for (int n = 0; n < 4; ++n) bRow[n] = (wn * 64 + n * 16 + fr) * 128;
#pragma unroll
  for (int kk = 0; kk < 2; ++kk) colx[kk] = (((kk * 4 + hi) ^ (fr & 7)) << 4);

  f32x4 acc[8][4] = {};

#pragma unroll
  for (int i = 0; i < 4; ++i) {
    gload_lds16(Ab + aG[i], &As[0][aL[i]]);
    gload_lds16(Bw + bG[i], &Bs[0][bL[i]]);
  }

  for (int kt = 0; kt < NKT; ++kt) {
    const int cur = kt & 1, nxt = cur ^ 1;
    __syncthreads();

    bf16x8 bf0[4], a0[4];
#pragma unroll
    for (int n = 0; n < 4; ++n)
      bf0[n] = *(const bf16x8*)((const void*)&Bs[cur][bRow[n] + colx[0]]);
#pragma unroll
    for (int m = 0; m < 4; ++m)
      a0[m] = *(const bf16x8*)((const void*)&As[cur][aRow[m] + colx[0]]);

    if (kt + 1 < NKT) {
      const int ko = (kt + 1) * 64;
#pragma unroll
      for (int i = 0; i < 4; ++i) {
        gload_lds16(Ab + aG[i] + ko, &As[nxt][aL[i]]);
        gload_lds16(Bw + bG[i] + ko, &Bs[nxt][bL[i]]);
      }
    }

    __builtin_amdgcn_s_setprio(1);
#pragma unroll
    for (int m = 0; m < 4; ++m)
#pragma unroll
      for (int n = 0; n < 4; ++n)
        acc[m][n] = __builtin_amdgcn_mfma_f32_16x16x32_bf16(a0[m], bf0[n], acc[m][n], 0, 0, 0);
    __builtin_amdgcn_s_setprio(0);
#pragma unroll
    for (int m = 0; m < 4; ++m)
      a0[m] = *(const bf16x8*)((const void*)&As[cur][aRow[4 + m] + colx[0]]);
    __builtin_amdgcn_s_setprio(1);
#pragma unroll
    for (int m = 0; m < 4; ++m)
#pragma unroll
      for (int n = 0; n < 4; ++n)
        acc[4 + m][n] = __builtin_amdgcn_mfma_f32_16x16x32_bf16(a0[m], bf0[n], acc[4 + m][n], 0, 0, 0);
    __builtin_amdgcn_s_setprio(0);

#pragma unroll
    for (int n = 0; n < 4; ++n)
      bf0[n] = *(const bf16x8*)((const void*)&Bs[cur][bRow[n] + colx[1]]);
#pragma unroll
    for (int m = 0; m < 4; ++m)
      a0[m] = *(const bf16x8*)((const void*)&As[cur][aRow[m] + colx[1]]);
    __builtin_amdgcn_s_setprio(1);
#pragma unroll
    for (int m = 0; m < 4; ++m)
#pragma unroll
      for (int n = 0; n < 4; ++n)
        acc[m][n] = __builtin_amdgcn_mfma_f32_16x16x32_bf16(a0[m], bf0[n], acc[m][n], 0, 0, 0);
    __builtin_amdgcn_s_setprio(0);
#pragma unroll
    for (int m = 0; m < 4; ++m)
      a0[m] = *(const bf16x8*)((const void*)&As[cur][aRow[4 + m] + colx[1]]);
    __builtin_amdgcn_s_setprio(1);
#pragma unroll
    for (int m = 0; m < 4; ++m)
#pragma unroll
      for (int n = 0; n < 4; ++n)
        acc[4 + m][n] = __builtin_amdgcn_mfma_f32_16x16x32_bf16(a0[m], bf0[n], acc[4 + m][n], 0, 0, 0);
    __builtin_amdgcn_s_setprio(0);
  }

  const int row0 = by * 256 + wm * 128 + hi * 4;
  const int col0 = bx * 256 + wn * 64 + fr;
#pragma unroll
  for (int n = 0; n < 4; ++n) {
    const int gc = col0 + n * 16;
    const float bv = bias[gc];
#pragma unroll
    for (int m = 0; m < 8; ++m) {
#pragma unroll
      for (int j = 0; j < 4; ++j) {
        const size_t idx = (size_t)(row0 + m * 16 + j) * NDIM + (size_t)gc;
        const float val = acc[m][n][j] + bv;
        if constexpr (OUT_F32)
          ((float*)Cv)[idx] = val;
        else
          ((u16*)Cv)[idx] = __builtin_bit_cast(u16, (__bf16)val);
      }
    }
  }
}

// One wave per (b,l,h) attention unit: 8x8 scores over DK=64, softmax over e,
// PV, write x in-place over q (disjoint columns per head -> race-free).
__global__ __launch_bounds__(256) void attn_kernel(u16* __restrict__ qx,
                                                   const u16* __restrict__ kb,
                                                   const u16* __restrict__ vb) {
  __shared__ __align__(16) u16 qs[4][8][64];
  __shared__ __align__(16) u16 ks[4][8][64];
  __shared__ __align__(16) u16 vs[4][8][64];
  const int t = threadIdx.x;
  const int lane = t & 63;
  const int w = t >> 6;
  const int unit = blockIdx.x * 4 + w;   // (b*L + l)*16 + h
  const int bl = unit >> 4;
  const int h = unit & 15;
  const int row = lane >> 3;
  const int c8 = (lane & 7) * 8;
  const size_t goff = (size_t)bl * 8 * 1024 + (size_t)h * 64 + (size_t)row * 1024 + c8;

  *(int4*)((void*)&qs[w][row][c8]) = *(const int4*)((const void*)&qx[goff]);
  *(int4*)((void*)&ks[w][row][c8]) = *(const int4*)((const void*)&kb[goff]);
  *(int4*)((void*)&vs[w][row][c8]) = *(const int4*)((const void*)&vb[goff]);
  __syncthreads();

  const int a = row;
  const int e = lane & 7;
  float s = 0.f;
#pragma unroll
  for (int d8 = 0; d8 < 64; d8 += 8) {
    const bf16x8 qv = *(const bf16x8*)((const void*)&qs[w][a][d8]);
    const bf16x8 kv = *(const bf16x8*)((const void*)&ks[w][e][d8]);
#pragma unroll
    for (int j = 0; j < 8; ++j) s += (float)qv[j] * (float)kv[j];
  }
  s *= 0.125f;

  float mx = s;
#pragma unroll
  for (int o = 1; o < 8; o <<= 1) mx = fmaxf(mx, __shfl_xor(mx, o));
  float p = __expf(s - mx);
  float sum = p;
#pragma unroll
  for (int o = 1; o < 8; o <<= 1) sum += __shfl_xor(sum, o);
  p /= sum;

  float xo[8] = {};
#pragma unroll
  for (int e2 = 0; e2 < 8; ++e2) {
    const float pe = __shfl(p, (lane & 56) + e2);
    const bf16x8 vv = *(const bf16x8*)((const void*)&vs[w][e2][c8]);
#pragma unroll
    for (int j = 0; j < 8; ++j) xo[j] += pe * (float)vv[j];
  }
  bf16x8 hx;
#pragma unroll
  for (int j = 0; j < 8; ++j) hx[j] = (__bf16)xo[j];
  *(int4*)((void*)&qx[goff]) = __builtin_bit_cast(int4, hx);
}

extern "C" void kernel_launch(void* const* d_in, const int* in_sizes, int n_in,
                              void* d_out, int out_size, void* d_ws, size_t ws_size,
                              hipStream_t stream) {
  const float* query = (const float*)d_in[0];
  const float* key   = (const float*)d_in[1];
  const float* value = (const float*)d_in[2];
  const float* Wq = (const float*)d_in[3];
  const float* bq = (const float*)d_in[4];
  const float* Wk = (const float*)d_in[5];
  const float* bk = (const float*)d_in[6];
  const float* Wv = (const float*)d_in[7];
  const float* bv = (const float*)d_in[8];
  const float* Wo = (const float*)d_in[9];
  const float* bo = (const float*)d_in[10];
  (void)in_sizes; (void)n_in; (void)out_size; (void)ws_size;

  const size_t mn = (size_t)MROWS * (size_t)NDIM;

  // d_out temporarily holds kb+vb (bf16), dead before final GEMM overwrites
  // d_out with fp32.
  // ws layout (108.6 MB): qb (67.1MB) | W bf16 x4 (8MB) | Abf slot (33.5MB,
  // reused serially by all six half-projections).
  u16* kb = (u16*)d_out;
  u16* vb = kb + mn;
  u16* qb = (u16*)d_ws;
  u16* Wqb = qb + mn;
  u16* Wkb = Wqb + 1048576;
  u16* Wvb = Wkb + 1048576;
  u16* Wob = Wvb + 1048576;
  u16* Abf = Wob + 1048576;

  CvtArgs ca;
  ca.s[0] = Wq; ca.s[1] = Wk; ca.s[2] = Wv; ca.s[3] = Wo;
  ca.d[0] = Wqb; ca.d[1] = Wkb; ca.d[2] = Wvb; ca.d[3] = Wob;
  cvt4_kernel<<<2048, 256, 0, stream>>>(ca);

  // Six half-projections (cvt -> GEMM), sharing the Abf slot (serialized
  // by stream order). Each half: M=16384 rows, 256 blocks = 1 block/CU.
  const float* srcs[3] = {key, value, query};
  const u16* wts[3] = {Wkb, Wvb, Wqb};
  const float* bss[3] = {bk, bv, bq};
  u16* outs[3] = {kb, vb, qb};
  for (int g = 0; g < 3; ++g) {
    for (int h = 0; h < 2; ++h) {
      cvt_half_kernel<<<8192, 256, 0, stream>>>(srcs[g] + (size_t)h * MHALF, Abf);
      gemm_bt256<false><<<256, 512, 0, stream>>>(
          Abf, wts[g], bss[g], (void*)(outs[g] + (size_t)h * MHALF), 8);
    }
  }

  attn_kernel<<<16384, 256, 0, stream>>>(qb, kb, vb);

  gemm_bt256<true><<<512, 512, 0, stream>>>(qb, Wob, bo, d_out, 16);
}

// Round 9
// 468.488 us; speedup vs baseline: 1.4469x; 1.0564x over previous
//
#include <hip/hip_runtime.h>
#include <hip/hip_bf16.h>
#include <stdint.h>

typedef unsigned short u16;
typedef __bf16 bf16x8 __attribute__((ext_vector_type(8)));
typedef float f32x4 __attribute__((ext_vector_type(4)));

// B=4, L=1024, A=8, D=1024, H=16, DK=64
#define MROWS 32768   // B*L*A
#define NDIM  1024
#define KDIM  1024
#define NKT   16      // K-tiles of BK=64
#define MHALF 16777216

__device__ __forceinline__ void gload_lds16(const void* g, void* l) {
  __builtin_amdgcn_global_load_lds(
      (__attribute__((address_space(1))) const void*)g,
      (__attribute__((address_space(3))) void*)l,
      16, 0, 0);
}

struct CvtArgs { const float* s[4]; u16* d[4]; };

__global__ __launch_bounds__(256) void cvt4_kernel(CvtArgs ca) {
  const int which = blockIdx.x >> 9;
  const float* s = ca.s[which];
  u16* d = ca.d[which];
  const int i = ((((int)blockIdx.x & 511) * 256) + (int)threadIdx.x) * 8;
  const float4 f0 = *(const float4*)(s + i);
  const float4 f1 = *(const float4*)(s + i + 4);
  bf16x8 h;
  h[0] = (__bf16)f0.x; h[1] = (__bf16)f0.y; h[2] = (__bf16)f0.z; h[3] = (__bf16)f0.w;
  h[4] = (__bf16)f1.x; h[5] = (__bf16)f1.y; h[6] = (__bf16)f1.z; h[7] = (__bf16)f1.w;
  *(bf16x8*)((void*)(d + i)) = h;
}

__global__ __launch_bounds__(256) void cvt_kernel(const float* __restrict__ s,
                                                  u16* __restrict__ d) {
  const int i = ((int)blockIdx.x * 256 + (int)threadIdx.x) * 8;
  const float4 f0 = *(const float4*)(s + i);
  const float4 f1 = *(const float4*)(s + i + 4);
  bf16x8 h;
  h[0] = (__bf16)f0.x; h[1] = (__bf16)f0.y; h[2] = (__bf16)f0.z; h[3] = (__bf16)f0.w;
  h[4] = (__bf16)f1.x; h[5] = (__bf16)f1.y; h[6] = (__bf16)f1.z; h[7] = (__bf16)f1.w;
  *(bf16x8*)((void*)(d + i)) = h;
}

// ---------------------------------------------------------------------------
// 8-phase 256x256 NT GEMM, BK=64, 512 thr (8 waves 2Mx4N), retry with the
// m201 template's slack constants:
//  - B-READ-ONCE: ph1/ph5 latch ALL 8 B-frags (b[0..7]) + 4 A-frags
//    (12 ds_reads) -> B LDS slots are register-latched after ph1/ph5.
//  - Stage windows (iter j; T1=2j+1,T2=2j+2,T3=2j+3; d = tile&1):
//      ph1: T1.Ah0(d1)  ph2: T1.Ah1(d1)   [A-d1 last read ph8(j-1)]
//      ph3: T2.Bh0(d0)  ph4: T2.Bh1(d0)   [B-d0 latched ph1]
//      ph5: T2.Ah0(d0)  ph6: T2.Ah1(d0)   [A-d0 last read ph4]
//      ph7: T3.Bh0(d1)  ph8: T3.Bh1(d1)   [B-d1 latched ph5]
//    Every stage >=1 full end-barrier after its slot's last read; no
//    same-phase read/write-slot overlap anywhere.
//  - vmcnt(4) at ph4/ph8 end (12 outstanding -> oldest 8 = next tile fully
//    landed, 2 half-tiles slack). Prologue: T0 x4 + T1.B x2, vmcnt(4).
//    Tail clamps T2/T3 to 15 (ledger exact; clamped stages follow the same
//    legal windows). vmcnt(0) after loop drains LDS writes before epilogue.
//  - sched_barrier(0) on both sides of every barrier/waitcnt (rule #18).
// Swizzle: chunk_phys = chunk ^ (row&7), both sides (proven 0-conflict).
// ---------------------------------------------------------------------------
#define SBAR0() __builtin_amdgcn_sched_barrier(0)
#define PH_SYNC() do { SBAR0(); __builtin_amdgcn_s_barrier(); \
    asm volatile("s_waitcnt lgkmcnt(0)" ::: "memory"); SBAR0(); } while (0)
#define PH_END() do { SBAR0(); __builtin_amdgcn_s_barrier(); } while (0)
#define VM4() asm volatile("s_waitcnt vmcnt(4)" ::: "memory")

template <bool OUT_F32>
__global__ __launch_bounds__(512, 2) void gemm8p(const u16* __restrict__ Ab,
                                                 const u16* __restrict__ Bw,
                                                 const float* __restrict__ bias,
                                                 void* __restrict__ Cv,
                                                 int byPerXcd) {
  __shared__ __align__(16) unsigned char As[2][2][16384];
  __shared__ __align__(16) unsigned char Bs[2][2][16384];

  const int bid = (int)blockIdx.x;
  const int xcd = bid & 7;
  const int within = bid >> 3;
  const int by = xcd * byPerXcd + (within >> 2);
  const int bx = within & 3;

  const int t = (int)threadIdx.x;
  const int lane = t & 63;
  const int wid = t >> 6;
  const int wm = wid >> 2;        // A-half (M)
  const int wn = wid & 3;
  const int bh = wn >> 1;         // B-half (N)
  const int fr = lane & 15;
  const int hi = lane >> 4;

  size_t gOff[2]; int lOff[2];
#pragma unroll
  for (int i = 0; i < 2; ++i) {
    const int idx = i * 512 + t;
    const int r = idx >> 3, ch = idx & 7;
    gOff[i] = (size_t)r * KDIM + (size_t)((ch ^ (r & 7)) << 3);
    lOff[i] = (i * 512 + (t & ~63)) * 16;
  }
  const u16* Abase = Ab + (size_t)(by * 256) * KDIM;
  const u16* Bbase = Bw + (size_t)(bx * 256) * KDIM;

  auto SA = [&](int tile, int d, int h) {
    const u16* s = Abase + (size_t)(h * 128) * KDIM + tile * 64;
#pragma unroll
    for (int i = 0; i < 2; ++i) gload_lds16(s + gOff[i], &As[d][h][lOff[i]]);
  };
  auto SB = [&](int tile, int d, int h) {
    const u16* s = Bbase + (size_t)(h * 128) * KDIM + tile * 64;
#pragma unroll
    for (int i = 0; i < 2; ++i) gload_lds16(s + gOff[i], &Bs[d][h][lOff[i]]);
  };

  int aOff[8][2], bOff[4][2];
#pragma unroll
  for (int m = 0; m < 8; ++m)
#pragma unroll
    for (int ks = 0; ks < 2; ++ks)
      aOff[m][ks] = (m * 16 + fr) * 128 + (((ks * 4 + hi) ^ (fr & 7)) << 4);
#pragma unroll
  for (int n = 0; n < 4; ++n)
#pragma unroll
    for (int ks = 0; ks < 2; ++ks)
      bOff[n][ks] = ((wn & 1) * 64 + n * 16 + fr) * 128 + (((ks * 4 + hi) ^ (fr & 7)) << 4);

  f32x4 acc[8][4] = {};
  bf16x8 a[4], b[8];

  const unsigned char* Am0 = &As[0][wm][0];
  const unsigned char* Am1 = &As[1][wm][0];
  const unsigned char* Bm0 = &Bs[0][bh][0];
  const unsigned char* Bm1 = &Bs[1][bh][0];

  auto LDA4_0 = [&](int mlo, int ks) {
#pragma unroll
    for (int i = 0; i < 4; ++i)
      a[i] = *(const bf16x8*)((const void*)(Am0 + aOff[mlo + i][ks]));
  };
  auto LDA4_1 = [&](int mlo, int ks) {
#pragma unroll
    for (int i = 0; i < 4; ++i)
      a[i] = *(const bf16x8*)((const void*)(Am1 + aOff[mlo + i][ks]));
  };
  auto LDB8_0 = [&]() {
#pragma unroll
    for (int ks = 0; ks < 2; ++ks)
#pragma unroll
      for (int n = 0; n < 4; ++n)
        b[ks * 4 + n] = *(const bf16x8*)((const void*)(Bm0 + bOff[n][ks]));
  };
  auto LDB8_1 = [&]() {
#pragma unroll
    for (int ks = 0; ks < 2; ++ks)
#pragma unroll
      for (int n = 0; n < 4; ++n)
        b[ks * 4 + n] = *(const bf16x8*)((const void*)(Bm1 + bOff[n][ks]));
  };
  auto MM = [&](int mlo, int bo) {
    __builtin_amdgcn_s_setprio(1);
#pragma unroll
    for (int m = 0; m < 4; ++m)
#pragma unroll
      for (int n = 0; n < 4; ++n)
        acc[mlo + m][n] = __builtin_amdgcn_mfma_f32_16x16x32_bf16(
            a[m], b[bo + n], acc[mlo + m][n], 0, 0, 0);
    __builtin_amdgcn_s_setprio(0);
  };

  // PROLOGUE: T0 all 4 halves + T1.B both halves; land T0 (vmcnt(4)).
  SB(0, 0, 0); SB(0, 0, 1); SA(0, 0, 0); SA(0, 0, 1);
  SB(1, 1, 0); SB(1, 1, 1);
  VM4(); SBAR0();
  __builtin_amdgcn_s_barrier();

  for (int j = 0; j < NKT / 2; ++j) {
    const int T1 = 2 * j + 1;
    const int T2 = (2 * j + 2 < NKT) ? 2 * j + 2 : NKT - 1;
    const int T3 = (2 * j + 3 < NKT) ? 2 * j + 3 : NKT - 1;

    // ---- tile 2j (d0) ----
    LDB8_0(); LDA4_0(0, 0);           // ph1: latch B all + A m0-3 ks0
    SA(T1, 1, 0);
    PH_SYNC(); MM(0, 0); PH_END();

    LDA4_0(4, 0);                     // ph2
    SA(T1, 1, 1);
    PH_SYNC(); MM(4, 0); PH_END();

    LDA4_0(0, 1);                     // ph3
    SB(T2, 0, 0);
    PH_SYNC(); MM(0, 4); PH_END();

    LDA4_0(4, 1);                     // ph4
    SB(T2, 0, 1);
    PH_SYNC(); MM(4, 4);
    VM4(); PH_END();                  // T1 fully landed

    // ---- tile 2j+1 (d1) ----
    LDB8_1(); LDA4_1(0, 0);           // ph5
    SA(T2, 0, 0);
    PH_SYNC(); MM(0, 0); PH_END();

    LDA4_1(4, 0);                     // ph6
    SA(T2, 0, 1);
    PH_SYNC(); MM(4, 0); PH_END();

    LDA4_1(0, 1);                     // ph7
    SB(T3, 1, 0);
    PH_SYNC(); MM(0, 4); PH_END();

    LDA4_1(4, 1);                     // ph8
    SB(T3, 1, 1);
    PH_SYNC(); MM(4, 4);
    VM4(); PH_END();                  // T2 fully landed
  }
  asm volatile("s_waitcnt vmcnt(0)" ::: "memory");

  // epilogue: D col = fr (N), row = hi*4 + jj (M)
  const int row0 = by * 256 + wm * 128 + hi * 4;
  const int col0 = bx * 256 + wn * 64 + fr;
#pragma unroll
  for (int n = 0; n < 4; ++n) {
    const int gc = col0 + n * 16;
    const float bv = bias[gc];
#pragma unroll
    for (int m = 0; m < 8; ++m) {
#pragma unroll
      for (int jj = 0; jj < 4; ++jj) {
        const size_t idx = (size_t)(row0 + m * 16 + jj) * NDIM + (size_t)gc;
        const float val = acc[m][n][jj] + bv;
        if constexpr (OUT_F32)
          ((float*)Cv)[idx] = val;
        else
          ((u16*)Cv)[idx] = __builtin_bit_cast(u16, (__bf16)val);
      }
    }
  }
}

// One wave per (b,l,h) attention unit: 8x8 scores over DK=64, softmax over e,
// PV, write x in-place over q (disjoint columns per head -> race-free).
__global__ __launch_bounds__(256) void attn_kernel(u16* __restrict__ qx,
                                                   const u16* __restrict__ kb,
                                                   const u16* __restrict__ vb) {
  __shared__ __align__(16) u16 qs[4][8][64];
  __shared__ __align__(16) u16 ks[4][8][64];
  __shared__ __align__(16) u16 vs[4][8][64];
  const int t = threadIdx.x;
  const int lane = t & 63;
  const int w = t >> 6;
  const int unit = blockIdx.x * 4 + w;
  const int bl = unit >> 4;
  const int h = unit & 15;
  const int row = lane >> 3;
  const int c8 = (lane & 7) * 8;
  const size_t goff = (size_t)bl * 8 * 1024 + (size_t)h * 64 + (size_t)row * 1024 + c8;

  *(int4*)((void*)&qs[w][row][c8]) = *(const int4*)((const void*)&qx[goff]);
  *(int4*)((void*)&ks[w][row][c8]) = *(const int4*)((const void*)&kb[goff]);
  *(int4*)((void*)&vs[w][row][c8]) = *(const int4*)((const void*)&vb[goff]);
  __syncthreads();

  const int a = row;
  const int e = lane & 7;
  float s = 0.f;
#pragma unroll
  for (int d8 = 0; d8 < 64; d8 += 8) {
    const bf16x8 qv = *(const bf16x8*)((const void*)&qs[w][a][d8]);
    const bf16x8 kv = *(const bf16x8*)((const void*)&ks[w][e][d8]);
#pragma unroll
    for (int j = 0; j < 8; ++j) s += (float)qv[j] * (float)kv[j];
  }
  s *= 0.125f;

  float mx = s;
#pragma unroll
  for (int o = 1; o < 8; o <<= 1) mx = fmaxf(mx, __shfl_xor(mx, o));
  float p = __expf(s - mx);
  float sum = p;
#pragma unroll
  for (int o = 1; o < 8; o <<= 1) sum += __shfl_xor(sum, o);
  p /= sum;

  float xo[8] = {};
#pragma unroll
  for (int e2 = 0; e2 < 8; ++e2) {
    const float pe = __shfl(p, (lane & 56) + e2);
    const bf16x8 vv = *(const bf16x8*)((const void*)&vs[w][e2][c8]);
#pragma unroll
    for (int j = 0; j < 8; ++j) xo[j] += pe * (float)vv[j];
  }
  bf16x8 hx;
#pragma unroll
  for (int j = 0; j < 8; ++j) hx[j] = (__bf16)xo[j];
  *(int4*)((void*)&qx[goff]) = __builtin_bit_cast(int4, hx);
}

extern "C" void kernel_launch(void* const* d_in, const int* in_sizes, int n_in,
                              void* d_out, int out_size, void* d_ws, size_t ws_size,
                              hipStream_t stream) {
  const float* query = (const float*)d_in[0];
  const float* key   = (const float*)d_in[1];
  const float* value = (const float*)d_in[2];
  const float* Wq = (const float*)d_in[3];
  const float* bq = (const float*)d_in[4];
  const float* Wk = (const float*)d_in[5];
  const float* bk = (const float*)d_in[6];
  const float* Wv = (const float*)d_in[7];
  const float* bv = (const float*)d_in[8];
  const float* Wo = (const float*)d_in[9];
  const float* bo = (const float*)d_in[10];
  (void)in_sizes; (void)n_in; (void)out_size; (void)ws_size;

  const size_t mn = (size_t)MROWS * (size_t)NDIM;

  // d_out temporarily holds kb+vb (bf16), dead before gemmo overwrites d_out
  // with fp32. ws: qb (67MB; also reused as bf16 staging for K/V inputs
  // before qb is written) | W bf16 x4 (8MB) | Abf (33.5MB, Q-half staging).
  u16* kb = (u16*)d_out;
  u16* vb = kb + mn;
  u16* qb = (u16*)d_ws;
  u16* Wqb = qb + mn;
  u16* Wkb = Wqb + 1048576;
  u16* Wvb = Wkb + 1048576;
  u16* Wob = Wvb + 1048576;
  u16* Abf = Wob + 1048576;

  CvtArgs ca;
  ca.s[0] = Wq; ca.s[1] = Wk; ca.s[2] = Wv; ca.s[3] = Wo;
  ca.d[0] = Wqb; ca.d[1] = Wkb; ca.d[2] = Wvb; ca.d[3] = Wob;
  cvt4_kernel<<<2048, 256, 0, stream>>>(ca);

  // K projection (key bf16-staged into the not-yet-written qb region)
  cvt_kernel<<<16384, 256, 0, stream>>>(key, qb);
  gemm8p<false><<<512, 512, 0, stream>>>(qb, Wkb, bk, (void*)kb, 16);
  // V projection
  cvt_kernel<<<16384, 256, 0, stream>>>(value, qb);
  gemm8p<false><<<512, 512, 0, stream>>>(qb, Wvb, bv, (void*)vb, 16);
  // Q projection in two halves via Abf (qb is the output now)
  cvt_kernel<<<8192, 256, 0, stream>>>(query, Abf);
  gemm8p<false><<<256, 512, 0, stream>>>(Abf, Wqb, bq, (void*)qb, 8);
  cvt_kernel<<<8192, 256, 0, stream>>>(query + MHALF, Abf);
  gemm8p<false><<<256, 512, 0, stream>>>(Abf, Wqb, bq, (void*)(qb + MHALF), 8);

  attn_kernel<<<16384, 256, 0, stream>>>(qb, kb, vb);

  gemm8p<true><<<512, 512, 0, stream>>>(qb, Wob, bo, d_out, 16);
}

// Round 10
// 455.886 us; speedup vs baseline: 1.4869x; 1.0276x over previous
//
#include <hip/hip_runtime.h>
#include <hip/hip_bf16.h>
#include <stdint.h>

typedef unsigned short u16;
typedef __bf16 bf16x8 __attribute__((ext_vector_type(8)));
typedef float f32x4 __attribute__((ext_vector_type(4)));

// B=4, L=1024, A=8, D=1024, H=16, DK=64
#define MROWS 32768   // B*L*A
#define NDIM  1024
#define KDIM  1024
#define NKT   16      // K-tiles of BK=64
#define MHALF 16777216

__device__ __forceinline__ void gload_lds16(const void* g, void* l) {
  __builtin_amdgcn_global_load_lds(
      (__attribute__((address_space(1))) const void*)g,
      (__attribute__((address_space(3))) void*)l,
      16, 0, 0);
}

struct CvtArgs { const float* s[4]; u16* d[4]; };

// Fused: blocks [0,16384) convert `key` (33.5M elems); blocks [16384,18432)
// convert the four 1M-elem weight matrices.
__global__ __launch_bounds__(256) void cvt_kw_kernel(const float* __restrict__ key,
                                                     u16* __restrict__ dkey,
                                                     CvtArgs ca) {
  const int bid = (int)blockIdx.x;
  const float* s; u16* d; int i;
  if (bid < 16384) {
    s = key; d = dkey;
    i = (bid * 256 + (int)threadIdx.x) * 8;
  } else {
    const int b2 = bid - 16384;
    const int which = b2 >> 9;
    s = ca.s[which]; d = ca.d[which];
    i = ((b2 & 511) * 256 + (int)threadIdx.x) * 8;
  }
  const float4 f0 = *(const float4*)(s + i);
  const float4 f1 = *(const float4*)(s + i + 4);
  bf16x8 h;
  h[0] = (__bf16)f0.x; h[1] = (__bf16)f0.y; h[2] = (__bf16)f0.z; h[3] = (__bf16)f0.w;
  h[4] = (__bf16)f1.x; h[5] = (__bf16)f1.y; h[6] = (__bf16)f1.z; h[7] = (__bf16)f1.w;
  *(bf16x8*)((void*)(d + i)) = h;
}

// ---------------------------------------------------------------------------
// 8-phase 256x256 NT GEMM (r9 structure, verified stable) + DRIBBLED CVT:
// per 2-K-tile iteration, each thread loads CVTP*2 float4 of the NEXT
// input at iter-top (oldest in the vmcnt FIFO -> drained by the existing
// VM4 waits with no extra stall; ledger re-verified) and stores CVTP bf16x8
// after ph8's VM4. Converts a 33.5MB half-input per dispatch "for free"
// under the compute (GEMM HBM util is only 7%).
//   CVTP=1: 512-block dispatch; CVTP=2: 256-block; CVTP=0: none.
// Core schedule unchanged from r9 (B-read-once, stage windows, vmcnt(4) at
// ph4/ph8, sched_barrier fencing, chunk^row&7 swizzle -> 0 conflicts).
// ---------------------------------------------------------------------------
#define SBAR0() __builtin_amdgcn_sched_barrier(0)
#define PH_SYNC() do { SBAR0(); __builtin_amdgcn_s_barrier(); \
    asm volatile("s_waitcnt lgkmcnt(0)" ::: "memory"); SBAR0(); } while (0)
#define PH_END() do { SBAR0(); __builtin_amdgcn_s_barrier(); } while (0)
#define VM4() asm volatile("s_waitcnt vmcnt(4)" ::: "memory")

template <bool OUT_F32, int CVTP>
__global__ __launch_bounds__(512, 2) void gemm8p(const u16* __restrict__ Ab,
                                                 const u16* __restrict__ Bw,
                                                 const float* __restrict__ bias,
                                                 void* __restrict__ Cv,
                                                 int byPerXcd,
                                                 const float* __restrict__ cvt_src,
                                                 u16* __restrict__ cvt_dst) {
  __shared__ __align__(16) unsigned char As[2][2][16384];
  __shared__ __align__(16) unsigned char Bs[2][2][16384];

  const int bid = (int)blockIdx.x;
  const int xcd = bid & 7;
  const int within = bid >> 3;
  const int by = xcd * byPerXcd + (within >> 2);
  const int bx = within & 3;

  const int t = (int)threadIdx.x;
  const int lane = t & 63;
  const int wid = t >> 6;
  const int wm = wid >> 2;        // A-half (M)
  const int wn = wid & 3;
  const int bh = wn >> 1;         // B-half (N)
  const int fr = lane & 15;
  const int hi = lane >> 4;

  size_t gOff[2]; int lOff[2];
#pragma unroll
  for (int i = 0; i < 2; ++i) {
    const int idx = i * 512 + t;
    const int r = idx >> 3, ch = idx & 7;
    gOff[i] = (size_t)r * KDIM + (size_t)((ch ^ (r & 7)) << 3);
    lOff[i] = (i * 512 + (t & ~63)) * 16;
  }
  const u16* Abase = Ab + (size_t)(by * 256) * KDIM;
  const u16* Bbase = Bw + (size_t)(bx * 256) * KDIM;

  auto SA = [&](int tile, int d, int h) {
    const u16* s = Abase + (size_t)(h * 128) * KDIM + tile * 64;
#pragma unroll
    for (int i = 0; i < 2; ++i) gload_lds16(s + gOff[i], &As[d][h][lOff[i]]);
  };
  auto SB = [&](int tile, int d, int h) {
    const u16* s = Bbase + (size_t)(h * 128) * KDIM + tile * 64;
#pragma unroll
    for (int i = 0; i < 2; ++i) gload_lds16(s + gOff[i], &Bs[d][h][lOff[i]]);
  };

  int aOff[8][2], bOff[4][2];
#pragma unroll
  for (int m = 0; m < 8; ++m)
#pragma unroll
    for (int ks = 0; ks < 2; ++ks)
      aOff[m][ks] = (m * 16 + fr) * 128 + (((ks * 4 + hi) ^ (fr & 7)) << 4);
#pragma unroll
  for (int n = 0; n < 4; ++n)
#pragma unroll
    for (int ks = 0; ks < 2; ++ks)
      bOff[n][ks] = ((wn & 1) * 64 + n * 16 + fr) * 128 + (((ks * 4 + hi) ^ (fr & 7)) << 4);

  f32x4 acc[8][4] = {};
  bf16x8 a[4], b[8];

  const unsigned char* Am0 = &As[0][wm][0];
  const unsigned char* Am1 = &As[1][wm][0];
  const unsigned char* Bm0 = &Bs[0][bh][0];
  const unsigned char* Bm1 = &Bs[1][bh][0];

  auto LDA4_0 = [&](int mlo, int ks) {
#pragma unroll
    for (int i = 0; i < 4; ++i)
      a[i] = *(const bf16x8*)((const void*)(Am0 + aOff[mlo + i][ks]));
  };
  auto LDA4_1 = [&](int mlo, int ks) {
#pragma unroll
    for (int i = 0; i < 4; ++i)
      a[i] = *(const bf16x8*)((const void*)(Am1 + aOff[mlo + i][ks]));
  };
  auto LDB8_0 = [&]() {
#pragma unroll
    for (int ks = 0; ks < 2; ++ks)
#pragma unroll
      for (int n = 0; n < 4; ++n)
        b[ks * 4 + n] = *(const bf16x8*)((const void*)(Bm0 + bOff[n][ks]));
  };
  auto LDB8_1 = [&]() {
#pragma unroll
    for (int ks = 0; ks < 2; ++ks)
#pragma unroll
      for (int n = 0; n < 4; ++n)
        b[ks * 4 + n] = *(const bf16x8*)((const void*)(Bm1 + bOff[n][ks]));
  };
  auto MM = [&](int mlo, int bo) {
    __builtin_amdgcn_s_setprio(1);
#pragma unroll
    for (int m = 0; m < 4; ++m)
#pragma unroll
      for (int n = 0; n < 4; ++n)
        acc[mlo + m][n] = __builtin_amdgcn_mfma_f32_16x16x32_bf16(
            a[m], b[bo + n], acc[mlo + m][n], 0, 0, 0);
    __builtin_amdgcn_s_setprio(0);
  };

  const int ngrid = (int)gridDim.x;

  // PROLOGUE: T0 all 4 halves + T1.B both halves; land T0 (vmcnt(4)).
  SB(0, 0, 0); SB(0, 0, 1); SA(0, 0, 0); SA(0, 0, 1);
  SB(1, 1, 0); SB(1, 1, 1);
  VM4(); SBAR0();
  __builtin_amdgcn_s_barrier();

  for (int j = 0; j < NKT / 2; ++j) {
    const int T1 = 2 * j + 1;
    const int T2 = (2 * j + 2 < NKT) ? 2 * j + 2 : NKT - 1;
    const int T3 = (2 * j + 3 < NKT) ? 2 * j + 3 : NKT - 1;

    // dribbled cvt: issue next-input loads FIRST (oldest in vmcnt FIFO ->
    // drained by VM4@ph4 with zero added wait).
    float4 cf[CVTP ? CVTP : 1][2];
    if constexpr (CVTP > 0) {
#pragma unroll
      for (int p = 0; p < CVTP; ++p) {
        const size_t b8i = ((size_t)(j * CVTP + p) * ngrid + bid) * 512 + t;
        cf[p][0] = ((const float4*)cvt_src)[b8i * 2];
        cf[p][1] = ((const float4*)cvt_src)[b8i * 2 + 1];
      }
    }

    // ---- tile 2j (d0) ----
    LDB8_0(); LDA4_0(0, 0);           // ph1: latch B all + A m0-3 ks0
    SA(T1, 1, 0);
    PH_SYNC(); MM(0, 0); PH_END();

    LDA4_0(4, 0);                     // ph2
    SA(T1, 1, 1);
    PH_SYNC(); MM(4, 0); PH_END();

    LDA4_0(0, 1);                     // ph3
    SB(T2, 0, 0);
    PH_SYNC(); MM(0, 4); PH_END();

    LDA4_0(4, 1);                     // ph4
    SB(T2, 0, 1);
    PH_SYNC(); MM(4, 4);
    VM4(); PH_END();                  // T1 fully landed

    // ---- tile 2j+1 (d1) ----
    LDB8_1(); LDA4_1(0, 0);           // ph5
    SA(T2, 0, 0);
    PH_SYNC(); MM(0, 0); PH_END();

    LDA4_1(4, 0);                     // ph6
    SA(T2, 0, 1);
    PH_SYNC(); MM(4, 0); PH_END();

    LDA4_1(0, 1);                     // ph7
    SB(T3, 1, 0);
    PH_SYNC(); MM(0, 4); PH_END();

    LDA4_1(4, 1);                     // ph8
    SB(T3, 1, 1);
    PH_SYNC(); MM(4, 4);
    VM4();                            // T2 fully landed

    // dribbled cvt stores: issued after VM4 (they become the oldest vmem
    // ops of the next iteration; drained long before the next VM4 matters).
    if constexpr (CVTP > 0) {
#pragma unroll
      for (int p = 0; p < CVTP; ++p) {
        const size_t b8i = ((size_t)(j * CVTP + p) * ngrid + bid) * 512 + t;
        bf16x8 h;
        h[0] = (__bf16)cf[p][0].x; h[1] = (__bf16)cf[p][0].y;
        h[2] = (__bf16)cf[p][0].z; h[3] = (__bf16)cf[p][0].w;
        h[4] = (__bf16)cf[p][1].x; h[5] = (__bf16)cf[p][1].y;
        h[6] = (__bf16)cf[p][1].z; h[7] = (__bf16)cf[p][1].w;
        *(bf16x8*)((void*)(cvt_dst + b8i * 8)) = h;
      }
    }
    PH_END();
  }
  asm volatile("s_waitcnt vmcnt(0)" ::: "memory");

  // epilogue: D col = fr (N), row = hi*4 + jj (M)
  const int row0 = by * 256 + wm * 128 + hi * 4;
  const int col0 = bx * 256 + wn * 64 + fr;
#pragma unroll
  for (int n = 0; n < 4; ++n) {
    const int gc = col0 + n * 16;
    const float bv = bias[gc];
#pragma unroll
    for (int m = 0; m < 8; ++m) {
#pragma unroll
      for (int jj = 0; jj < 4; ++jj) {
        const size_t idx = (size_t)(row0 + m * 16 + jj) * NDIM + (size_t)gc;
        const float val = acc[m][n][jj] + bv;
        if constexpr (OUT_F32)
          ((float*)Cv)[idx] = val;
        else
          ((u16*)Cv)[idx] = __builtin_bit_cast(u16, (__bf16)val);
      }
    }
  }
}

// One wave per (b,l,h) attention unit: 8x8 scores over DK=64, softmax over e,
// PV, write x in-place over q (disjoint columns per head -> race-free).
__global__ __launch_bounds__(256) void attn_kernel(u16* __restrict__ qx,
                                                   const u16* __restrict__ kb,
                                                   const u16* __restrict__ vb) {
  __shared__ __align__(16) u16 qs[4][8][64];
  __shared__ __align__(16) u16 ks[4][8][64];
  __shared__ __align__(16) u16 vs[4][8][64];
  const int t = threadIdx.x;
  const int lane = t & 63;
  const int w = t >> 6;
  const int unit = blockIdx.x * 4 + w;
  const int bl = unit >> 4;
  const int h = unit & 15;
  const int row = lane >> 3;
  const int c8 = (lane & 7) * 8;
  const size_t goff = (size_t)bl * 8 * 1024 + (size_t)h * 64 + (size_t)row * 1024 + c8;

  *(int4*)((void*)&qs[w][row][c8]) = *(const int4*)((const void*)&qx[goff]);
  *(int4*)((void*)&ks[w][row][c8]) = *(const int4*)((const void*)&kb[goff]);
  *(int4*)((void*)&vs[w][row][c8]) = *(const int4*)((const void*)&vb[goff]);
  __syncthreads();

  const int a = row;
  const int e = lane & 7;
  float s = 0.f;
#pragma unroll
  for (int d8 = 0; d8 < 64; d8 += 8) {
    const bf16x8 qv = *(const bf16x8*)((const void*)&qs[w][a][d8]);
    const bf16x8 kv = *(const bf16x8*)((const void*)&ks[w][e][d8]);
#pragma unroll
    for (int j = 0; j < 8; ++j) s += (float)qv[j] * (float)kv[j];
  }
  s *= 0.125f;

  float mx = s;
#pragma unroll
  for (int o = 1; o < 8; o <<= 1) mx = fmaxf(mx, __shfl_xor(mx, o));
  float p = __expf(s - mx);
  float sum = p;
#pragma unroll
  for (int o = 1; o < 8; o <<= 1) sum += __shfl_xor(sum, o);
  p /= sum;

  float xo[8] = {};
#pragma unroll
  for (int e2 = 0; e2 < 8; ++e2) {
    const float pe = __shfl(p, (lane & 56) + e2);
    const bf16x8 vv = *(const bf16x8*)((const void*)&vs[w][e2][c8]);
#pragma unroll
    for (int j = 0; j < 8; ++j) xo[j] += pe * (float)vv[j];
  }
  bf16x8 hx;
#pragma unroll
  for (int j = 0; j < 8; ++j) hx[j] = (__bf16)xo[j];
  *(int4*)((void*)&qx[goff]) = __builtin_bit_cast(int4, hx);
}

extern "C" void kernel_launch(void* const* d_in, const int* in_sizes, int n_in,
                              void* d_out, int out_size, void* d_ws, size_t ws_size,
                              hipStream_t stream) {
  const float* query = (const float*)d_in[0];
  const float* key   = (const float*)d_in[1];
  const float* value = (const float*)d_in[2];
  const float* Wq = (const float*)d_in[3];
  const float* bq = (const float*)d_in[4];
  const float* Wk = (const float*)d_in[5];
  const float* bk = (const float*)d_in[6];
  const float* Wv = (const float*)d_in[7];
  const float* bv = (const float*)d_in[8];
  const float* Wo = (const float*)d_in[9];
  const float* bo = (const float*)d_in[10];
  (void)in_sizes; (void)n_in; (void)out_size; (void)ws_size;

  const size_t mn = (size_t)MROWS * (size_t)NDIM;

  // d_out temporarily holds kb+vb (bf16), dead before gemmo overwrites d_out
  // with fp32. ws: qb (67MB) | W bf16 x4 (8MB) | Abf (33.5MB).
  // Staging slot lifetimes (all verified disjoint per-launch):
  //   L2 cvtKW: key->qb(full), weights.
  //   L3 gemmK:   reads qb,     writes kb;        cvt value_h1 -> Abf
  //   L4 gemmV_h1: reads Abf,   writes vb_lo;     cvt value_h2 -> qb_lo
  //   L5 gemmV_h2: reads qb_lo, writes vb_hi;     cvt query_h1 -> qb_hi
  //   L6 gemmQ_h1: reads qb_hi, writes qb_lo;     cvt query_h2 -> Abf
  //   L7 gemmQ_h2: reads Abf,   writes qb_hi
  u16* kb = (u16*)d_out;
  u16* vb = kb + mn;
  u16* qb = (u16*)d_ws;
  u16* Wqb = qb + mn;
  u16* Wkb = Wqb + 1048576;
  u16* Wvb = Wkb + 1048576;
  u16* Wob = Wvb + 1048576;
  u16* Abf = Wob + 1048576;
  u16* qb_hi = qb + MHALF;

  CvtArgs ca;
  ca.s[0] = Wq; ca.s[1] = Wk; ca.s[2] = Wv; ca.s[3] = Wo;
  ca.d[0] = Wqb; ca.d[1] = Wkb; ca.d[2] = Wvb; ca.d[3] = Wob;
  cvt_kw_kernel<<<18432, 256, 0, stream>>>(key, qb, ca);

  // K projection; hides cvt(value_h1) -> Abf.
  gemm8p<false, 1><<<512, 512, 0, stream>>>(qb, Wkb, bk, (void*)kb, 16,
                                            value, Abf);
  // V projection halves; hide cvt(value_h2) and cvt(query_h1).
  gemm8p<false, 2><<<256, 512, 0, stream>>>(Abf, Wvb, bv, (void*)vb, 8,
                                            value + MHALF, qb);
  gemm8p<false, 2><<<256, 512, 0, stream>>>(qb, Wvb, bv, (void*)(vb + MHALF), 8,
                                            query, qb_hi);
  // Q projection halves; h1 hides cvt(query_h2) -> Abf.
  gemm8p<false, 2><<<256, 512, 0, stream>>>(qb_hi, Wqb, bq, (void*)qb, 8,
                                            query + MHALF, Abf);
  gemm8p<false, 0><<<256, 512, 0, stream>>>(Abf, Wqb, bq, (void*)qb_hi, 8,
                                            nullptr, nullptr);

  attn_kernel<<<16384, 256, 0, stream>>>(qb, kb, vb);

  gemm8p<true, 0><<<512, 512, 0, stream>>>(qb, Wob, bo, d_out, 16,
                                           nullptr, nullptr);
}

// Round 11
// 452.866 us; speedup vs baseline: 1.4968x; 1.0067x over previous
//
#include <hip/hip_runtime.h>
#include <hip/hip_bf16.h>
#include <stdint.h>

typedef unsigned short u16;
typedef __bf16 bf16x8 __attribute__((ext_vector_type(8)));
typedef float f32x4 __attribute__((ext_vector_type(4)));

// B=4, L=1024, A=8, D=1024, H=16, DK=64
#define MROWS 32768   // B*L*A
#define NDIM  1024
#define KDIM  1024
#define NKT   16      // K-tiles of BK=64
#define MHALF 16777216

__device__ __forceinline__ void gload_lds16(const void* g, void* l) {
  __builtin_amdgcn_global_load_lds(
      (__attribute__((address_space(1))) const void*)g,
      (__attribute__((address_space(3))) void*)l,
      16, 0, 0);
}

struct CvtArgs { const float* s[4]; u16* d[4]; };

// Fused: blocks [0,8192) convert key_h1 (16.78M elems); blocks [8192,10240)
// convert the four 1M-elem weight matrices.
__global__ __launch_bounds__(256) void cvt_kw_kernel(const float* __restrict__ key,
                                                     u16* __restrict__ dkey,
                                                     CvtArgs ca) {
  const int bid = (int)blockIdx.x;
  const float* s; u16* d; int i;
  if (bid < 8192) {
    s = key; d = dkey;
    i = (bid * 256 + (int)threadIdx.x) * 8;
  } else {
    const int b2 = bid - 8192;
    const int which = b2 >> 9;
    s = ca.s[which]; d = ca.d[which];
    i = ((b2 & 511) * 256 + (int)threadIdx.x) * 8;
  }
  const float4 f0 = *(const float4*)(s + i);
  const float4 f1 = *(const float4*)(s + i + 4);
  bf16x8 h;
  h[0] = (__bf16)f0.x; h[1] = (__bf16)f0.y; h[2] = (__bf16)f0.z; h[3] = (__bf16)f0.w;
  h[4] = (__bf16)f1.x; h[5] = (__bf16)f1.y; h[6] = (__bf16)f1.z; h[7] = (__bf16)f1.w;
  *(bf16x8*)((void*)(d + i)) = h;
}

// ---------------------------------------------------------------------------
// 8-phase 256x256 NT GEMM (r9/r10 structure, verified stable across timed
// replays) + dribbled cvt (r10, verified): per 2-K-tile iteration each
// thread loads CVTP*2 float4 of the NEXT input at iter-top (drained by the
// existing VM4 waits; ledger verified) and stores CVTP bf16x8 after ph8's
// VM4. Core schedule: B-read-once (ph1/ph5 latch all 8 B-frags), stage
// windows ph1-2->T1.A(d1), ph3-4->T2.B(d0), ph5-6->T2.A(d0), ph7-8->T3.B(d1),
// vmcnt(4) at ph4/ph8 only, sched_barrier(0) fencing, chunk^(row&7) LDS
// swizzle on both sides (0 conflicts measured).
// ---------------------------------------------------------------------------
#define SBAR0() __builtin_amdgcn_sched_barrier(0)
#define PH_SYNC() do { SBAR0(); __builtin_amdgcn_s_barrier(); \
    asm volatile("s_waitcnt lgkmcnt(0)" ::: "memory"); SBAR0(); } while (0)
#define PH_END() do { SBAR0(); __builtin_amdgcn_s_barrier(); } while (0)
#define VM4() asm volatile("s_waitcnt vmcnt(4)" ::: "memory")

template <bool OUT_F32, int CVTP>
__global__ __launch_bounds__(512, 2) void gemm8p(const u16* __restrict__ Ab,
                                                 const u16* __restrict__ Bw,
                                                 const float* __restrict__ bias,
                                                 void* __restrict__ Cv,
                                                 int byPerXcd,
                                                 const float* __restrict__ cvt_src,
                                                 u16* __restrict__ cvt_dst) {
  __shared__ __align__(16) unsigned char As[2][2][16384];
  __shared__ __align__(16) unsigned char Bs[2][2][16384];

  const int bid = (int)blockIdx.x;
  const int xcd = bid & 7;
  const int within = bid >> 3;
  const int by = xcd * byPerXcd + (within >> 2);
  const int bx = within & 3;

  const int t = (int)threadIdx.x;
  const int lane = t & 63;
  const int wid = t >> 6;
  const int wm = wid >> 2;        // A-half (M)
  const int wn = wid & 3;
  const int bh = wn >> 1;         // B-half (N)
  const int fr = lane & 15;
  const int hi = lane >> 4;

  size_t gOff[2]; int lOff[2];
#pragma unroll
  for (int i = 0; i < 2; ++i) {
    const int idx = i * 512 + t;
    const int r = idx >> 3, ch = idx & 7;
    gOff[i] = (size_t)r * KDIM + (size_t)((ch ^ (r & 7)) << 3);
    lOff[i] = (i * 512 + (t & ~63)) * 16;
  }
  const u16* Abase = Ab + (size_t)(by * 256) * KDIM;
  const u16* Bbase = Bw + (size_t)(bx * 256) * KDIM;

  auto SA = [&](int tile, int d, int h) {
    const u16* s = Abase + (size_t)(h * 128) * KDIM + tile * 64;
#pragma unroll
    for (int i = 0; i < 2; ++i) gload_lds16(s + gOff[i], &As[d][h][lOff[i]]);
  };
  auto SB = [&](int tile, int d, int h) {
    const u16* s = Bbase + (size_t)(h * 128) * KDIM + tile * 64;
#pragma unroll
    for (int i = 0; i < 2; ++i) gload_lds16(s + gOff[i], &Bs[d][h][lOff[i]]);
  };

  int aOff[8][2], bOff[4][2];
#pragma unroll
  for (int m = 0; m < 8; ++m)
#pragma unroll
    for (int ks = 0; ks < 2; ++ks)
      aOff[m][ks] = (m * 16 + fr) * 128 + (((ks * 4 + hi) ^ (fr & 7)) << 4);
#pragma unroll
  for (int n = 0; n < 4; ++n)
#pragma unroll
    for (int ks = 0; ks < 2; ++ks)
      bOff[n][ks] = ((wn & 1) * 64 + n * 16 + fr) * 128 + (((ks * 4 + hi) ^ (fr & 7)) << 4);

  f32x4 acc[8][4] = {};
  bf16x8 a[4], b[8];

  const unsigned char* Am0 = &As[0][wm][0];
  const unsigned char* Am1 = &As[1][wm][0];
  const unsigned char* Bm0 = &Bs[0][bh][0];
  const unsigned char* Bm1 = &Bs[1][bh][0];

  auto LDA4_0 = [&](int mlo, int ks) {
#pragma unroll
    for (int i = 0; i < 4; ++i)
      a[i] = *(const bf16x8*)((const void*)(Am0 + aOff[mlo + i][ks]));
  };
  auto LDA4_1 = [&](int mlo, int ks) {
#pragma unroll
    for (int i = 0; i < 4; ++i)
      a[i] = *(const bf16x8*)((const void*)(Am1 + aOff[mlo + i][ks]));
  };
  auto LDB8_0 = [&]() {
#pragma unroll
    for (int ks = 0; ks < 2; ++ks)
#pragma unroll
      for (int n = 0; n < 4; ++n)
        b[ks * 4 + n] = *(const bf16x8*)((const void*)(Bm0 + bOff[n][ks]));
  };
  auto LDB8_1 = [&]() {
#pragma unroll
    for (int ks = 0; ks < 2; ++ks)
#pragma unroll
      for (int n = 0; n < 4; ++n)
        b[ks * 4 + n] = *(const bf16x8*)((const void*)(Bm1 + bOff[n][ks]));
  };
  auto MM = [&](int mlo, int bo) {
    __builtin_amdgcn_s_setprio(1);
#pragma unroll
    for (int m = 0; m < 4; ++m)
#pragma unroll
      for (int n = 0; n < 4; ++n)
        acc[mlo + m][n] = __builtin_amdgcn_mfma_f32_16x16x32_bf16(
            a[m], b[bo + n], acc[mlo + m][n], 0, 0, 0);
    __builtin_amdgcn_s_setprio(0);
  };

  const int ngrid = (int)gridDim.x;

  // PROLOGUE: T0 all 4 halves + T1.B both halves; land T0 (vmcnt(4)).
  SB(0, 0, 0); SB(0, 0, 1); SA(0, 0, 0); SA(0, 0, 1);
  SB(1, 1, 0); SB(1, 1, 1);
  VM4(); SBAR0();
  __builtin_amdgcn_s_barrier();

  for (int j = 0; j < NKT / 2; ++j) {
    const int T1 = 2 * j + 1;
    const int T2 = (2 * j + 2 < NKT) ? 2 * j + 2 : NKT - 1;
    const int T3 = (2 * j + 3 < NKT) ? 2 * j + 3 : NKT - 1;

    // dribbled cvt: issue next-input loads FIRST (oldest in vmcnt FIFO ->
    // drained by VM4@ph4 with no added ledger slack).
    float4 cf[CVTP ? CVTP : 1][2];
    if constexpr (CVTP > 0) {
#pragma unroll
      for (int p = 0; p < CVTP; ++p) {
        const size_t b8i = ((size_t)(j * CVTP + p) * ngrid + bid) * 512 + t;
        cf[p][0] = ((const float4*)cvt_src)[b8i * 2];
        cf[p][1] = ((const float4*)cvt_src)[b8i * 2 + 1];
      }
    }

    // ---- tile 2j (d0) ----
    LDB8_0(); LDA4_0(0, 0);           // ph1: latch B all + A m0-3 ks0
    SA(T1, 1, 0);
    PH_SYNC(); MM(0, 0); PH_END();

    LDA4_0(4, 0);                     // ph2
    SA(T1, 1, 1);
    PH_SYNC(); MM(4, 0); PH_END();

    LDA4_0(0, 1);                     // ph3
    SB(T2, 0, 0);
    PH_SYNC(); MM(0, 4); PH_END();

    LDA4_0(4, 1);                     // ph4
    SB(T2, 0, 1);
    PH_SYNC(); MM(4, 4);
    VM4(); PH_END();                  // T1 fully landed

    // ---- tile 2j+1 (d1) ----
    LDB8_1(); LDA4_1(0, 0);           // ph5
    SA(T2, 0, 0);
    PH_SYNC(); MM(0, 0); PH_END();

    LDA4_1(4, 0);                     // ph6
    SA(T2, 0, 1);
    PH_SYNC(); MM(4, 0); PH_END();

    LDA4_1(0, 1);                     // ph7
    SB(T3, 1, 0);
    PH_SYNC(); MM(0, 4); PH_END();

    LDA4_1(4, 1);                     // ph8
    SB(T3, 1, 1);
    PH_SYNC(); MM(4, 4);
    VM4();                            // T2 fully landed

    // dribbled cvt stores after VM4 (become oldest vmem of next iter).
    if constexpr (CVTP > 0) {
#pragma unroll
      for (int p = 0; p < CVTP; ++p) {
        const size_t b8i = ((size_t)(j * CVTP + p) * ngrid + bid) * 512 + t;
        bf16x8 h;
        h[0] = (__bf16)cf[p][0].x; h[1] = (__bf16)cf[p][0].y;
        h[2] = (__bf16)cf[p][0].z; h[3] = (__bf16)cf[p][0].w;
        h[4] = (__bf16)cf[p][1].x; h[5] = (__bf16)cf[p][1].y;
        h[6] = (__bf16)cf[p][1].z; h[7] = (__bf16)cf[p][1].w;
        *(bf16x8*)((void*)(cvt_dst + b8i * 8)) = h;
      }
    }
    PH_END();
  }
  asm volatile("s_waitcnt vmcnt(0)" ::: "memory");

  // epilogue: D col = fr (N), row = hi*4 + jj (M)
  const int row0 = by * 256 + wm * 128 + hi * 4;
  const int col0 = bx * 256 + wn * 64 + fr;
#pragma unroll
  for (int n = 0; n < 4; ++n) {
    const int gc = col0 + n * 16;
    const float bv = bias[gc];
#pragma unroll
    for (int m = 0; m < 8; ++m) {
#pragma unroll
      for (int jj = 0; jj < 4; ++jj) {
        const size_t idx = (size_t)(row0 + m * 16 + jj) * NDIM + (size_t)gc;
        const float val = acc[m][n][jj] + bv;
        if constexpr (OUT_F32)
          ((float*)Cv)[idx] = val;
        else
          ((u16*)Cv)[idx] = __builtin_bit_cast(u16, (__bf16)val);
      }
    }
  }
}

// One wave per (b,l,h) attention unit: 8x8 scores over DK=64, softmax over e,
// PV, write x in-place over q (disjoint columns per head -> race-free).
__global__ __launch_bounds__(256) void attn_kernel(u16* __restrict__ qx,
                                                   const u16* __restrict__ kb,
                                                   const u16* __restrict__ vb) {
  __shared__ __align__(16) u16 qs[4][8][64];
  __shared__ __align__(16) u16 ks[4][8][64];
  __shared__ __align__(16) u16 vs[4][8][64];
  const int t = threadIdx.x;
  const int lane = t & 63;
  const int w = t >> 6;
  const int unit = blockIdx.x * 4 + w;
  const int bl = unit >> 4;
  const int h = unit & 15;
  const int row = lane >> 3;
  const int c8 = (lane & 7) * 8;
  const size_t goff = (size_t)bl * 8 * 1024 + (size_t)h * 64 + (size_t)row * 1024 + c8;

  *(int4*)((void*)&qs[w][row][c8]) = *(const int4*)((const void*)&qx[goff]);
  *(int4*)((void*)&ks[w][row][c8]) = *(const int4*)((const void*)&kb[goff]);
  *(int4*)((void*)&vs[w][row][c8]) = *(const int4*)((const void*)&vb[goff]);
  __syncthreads();

  const int a = row;
  const int e = lane & 7;
  float s = 0.f;
#pragma unroll
  for (int d8 = 0; d8 < 64; d8 += 8) {
    const bf16x8 qv = *(const bf16x8*)((const void*)&qs[w][a][d8]);
    const bf16x8 kv = *(const bf16x8*)((const void*)&ks[w][e][d8]);
#pragma unroll
    for (int j = 0; j < 8; ++j) s += (float)qv[j] * (float)kv[j];
  }
  s *= 0.125f;

  float mx = s;
#pragma unroll
  for (int o = 1; o < 8; o <<= 1) mx = fmaxf(mx, __shfl_xor(mx, o));
  float p = __expf(s - mx);
  float sum = p;
#pragma unroll
  for (int o = 1; o < 8; o <<= 1) sum += __shfl_xor(sum, o);
  p /= sum;

  float xo[8] = {};
#pragma unroll
  for (int e2 = 0; e2 < 8; ++e2) {
    const float pe = __shfl(p, (lane & 56) + e2);
    const bf16x8 vv = *(const bf16x8*)((const void*)&vs[w][e2][c8]);
#pragma unroll
    for (int j = 0; j < 8; ++j) xo[j] += pe * (float)vv[j];
  }
  bf16x8 hx;
#pragma unroll
  for (int j = 0; j < 8; ++j) hx[j] = (__bf16)xo[j];
  *(int4*)((void*)&qx[goff]) = __builtin_bit_cast(int4, hx);
}

extern "C" void kernel_launch(void* const* d_in, const int* in_sizes, int n_in,
                              void* d_out, int out_size, void* d_ws, size_t ws_size,
                              hipStream_t stream) {
  const float* query = (const float*)d_in[0];
  const float* key   = (const float*)d_in[1];
  const float* value = (const float*)d_in[2];
  const float* Wq = (const float*)d_in[3];
  const float* bq = (const float*)d_in[4];
  const float* Wk = (const float*)d_in[5];
  const float* bk = (const float*)d_in[6];
  const float* Wv = (const float*)d_in[7];
  const float* bv = (const float*)d_in[8];
  const float* Wo = (const float*)d_in[9];
  const float* bo = (const float*)d_in[10];
  (void)in_sizes; (void)n_in; (void)out_size; (void)ws_size;

  const size_t mn = (size_t)MROWS * (size_t)NDIM;

  // d_out temporarily holds kb+vb (bf16), dead before gemmo overwrites d_out
  // with fp32. ws: qb (67MB) | W bf16 x4 (8MB) | Abf (33.5MB).
  // Pipeline (each line: reads -> writes ; dribbled cvt):
  //   L1 cvtKW:    key_h1 -> qb_lo ; weights
  //   L2 gemmK_h1: qb_lo  -> kb_lo ; cvt key_h2   -> qb_hi
  //   L3 gemmK_h2: qb_hi  -> kb_hi ; cvt value_h1 -> Abf
  //   L4 gemmV_h1: Abf    -> vb_lo ; cvt value_h2 -> qb_lo   (key_h1 dead)
  //   L5 gemmV_h2: qb_lo  -> vb_hi ; cvt query_h1 -> qb_hi   (key_h2 dead)
  //   L6 gemmQ_h1: qb_hi  -> qb_lo ; cvt query_h2 -> Abf     (value_h1 dead)
  //   L7 gemmQ_h2: Abf    -> qb_hi
  //   L8 attn(qb, kb, vb) in-place x -> qb
  //   L9 gemmo:    qb -> d_out fp32
  u16* kb = (u16*)d_out;
  u16* vb = kb + mn;
  u16* qb = (u16*)d_ws;
  u16* Wqb = qb + mn;
  u16* Wkb = Wqb + 1048576;
  u16* Wvb = Wkb + 1048576;
  u16* Wob = Wvb + 1048576;
  u16* Abf = Wob + 1048576;
  u16* qb_hi = qb + MHALF;

  CvtArgs ca;
  ca.s[0] = Wq; ca.s[1] = Wk; ca.s[2] = Wv; ca.s[3] = Wo;
  ca.d[0] = Wqb; ca.d[1] = Wkb; ca.d[2] = Wvb; ca.d[3] = Wob;
  cvt_kw_kernel<<<10240, 256, 0, stream>>>(key, qb, ca);

  gemm8p<false, 2><<<256, 512, 0, stream>>>(qb, Wkb, bk, (void*)kb, 8,
                                            key + MHALF, qb_hi);
  gemm8p<false, 2><<<256, 512, 0, stream>>>(qb_hi, Wkb, bk, (void*)(kb + MHALF), 8,
                                            value, Abf);
  gemm8p<false, 2><<<256, 512, 0, stream>>>(Abf, Wvb, bv, (void*)vb, 8,
                                            value + MHALF, qb);
  gemm8p<false, 2><<<256, 512, 0, stream>>>(qb, Wvb, bv, (void*)(vb + MHALF), 8,
                                            query, qb_hi);
  gemm8p<false, 2><<<256, 512, 0, stream>>>(qb_hi, Wqb, bq, (void*)qb, 8,
                                            query + MHALF, Abf);
  gemm8p<false, 0><<<256, 512, 0, stream>>>(Abf, Wqb, bq, (void*)qb_hi, 8,
                                            nullptr, nullptr);

  attn_kernel<<<16384, 256, 0, stream>>>(qb, kb, vb);

  gemm8p<true, 0><<<512, 512, 0, stream>>>(qb, Wob, bo, d_out, 16,
                                           nullptr, nullptr);
}